// Round 3
// baseline (9724.090 us; speedup 1.0000x reference)
//
#include <hip/hip_runtime.h>
#include <math.h>

#define B_   64
#define T_   128
#define NIN  256
#define H_   512
#define O_   256
#define M_   64
#define R_   512
#define EPS_ 1e-8f
#define NWG  64

__device__ __forceinline__ float dot4(float4 a, float4 b) {
    return a.x*b.x + a.y*b.y + a.z*b.z + a.w*b.w;
}

template<int CTRL>
__device__ __forceinline__ float dpp_add(float v) {
    int t = __builtin_amdgcn_update_dpp(0, __float_as_int(v), CTRL, 0xF, 0xF, false);
    return v + __int_as_float(t);
}
__device__ __forceinline__ float red4(float v) {   // sum over lane quads
    v = dpp_add<0xB1>(v);    // quad_perm xor1
    v = dpp_add<0x4E>(v);    // quad_perm xor2
    return v;
}
__device__ __forceinline__ float red16(float v) {  // sum over 16-lane rows
    v = dpp_add<0xB1>(v);
    v = dpp_add<0x4E>(v);
    v = dpp_add<0x124>(v);   // row_ror:4
    v = dpp_add<0x128>(v);   // row_ror:8
    return v;
}
__device__ __forceinline__ float tanh_f(float x)    { float e = __expf(2.f * x); return 1.f - 2.f / (e + 1.f); }
__device__ __forceinline__ float sigmoid_f(float x) { return 1.f / (1.f + __expf(-x)); }
__device__ __forceinline__ float softplus_f(float x){ return x > 20.f ? x : log1pf(__expf(x)); }

// ---------------- Kernel 1: xin[bt][i] = x[bt] @ W_in.T + b_in ----------------
__global__ __launch_bounds__(256) void xin_gemm(
    const float* __restrict__ x, const float* __restrict__ Win,
    const float* __restrict__ bin, float* __restrict__ xin)
{
    __shared__ __align__(16) float xs[32 * NIN];
    const int tid  = threadIdx.x;
    const int row0 = blockIdx.x * 32;

    #pragma unroll
    for (int i = 0; i < 8; ++i) {
        int idx = i * 1024 + tid * 4;
        *(float4*)&xs[idx] = *(const float4*)&x[(size_t)row0 * NIN + idx];
    }
    __syncthreads();

    const int rg = tid >> 6;
    const int cg = tid & 63;
    const int c0 = cg * 8;
    float acc[8][8];
    #pragma unroll
    for (int r = 0; r < 8; ++r)
        #pragma unroll
        for (int c = 0; c < 8; ++c) acc[r][c] = 0.f;

    for (int k = 0; k < NIN; k += 4) {
        float4 xq[8];
        #pragma unroll
        for (int r = 0; r < 8; ++r) xq[r] = *(float4*)&xs[(rg * 8 + r) * NIN + k];
        #pragma unroll
        for (int c = 0; c < 8; ++c) {
            float4 w4 = *(const float4*)&Win[(size_t)(c0 + c) * NIN + k];
            #pragma unroll
            for (int r = 0; r < 8; ++r) acc[r][c] += dot4(xq[r], w4);
        }
    }
    #pragma unroll
    for (int r = 0; r < 8; ++r) {
        int grow = row0 + rg * 8 + r;
        #pragma unroll
        for (int c = 0; c < 8; ++c)
            xin[(size_t)grow * H_ + c0 + c] = acc[r][c] + bin[c0 + c];
    }
}

// grid sync: device-scope arrive + spin on a monotonic counter (guarded)
__device__ __forceinline__ void gridsync(unsigned* ctr, unsigned target, bool& alive) {
    __syncthreads();
    if (threadIdx.x == 0) {
        __threadfence();   // release: make this WG's stores device-visible
        __hip_atomic_fetch_add(ctr, 1u, __ATOMIC_RELEASE, __HIP_MEMORY_SCOPE_AGENT);
        if (alive) {
            int guard = 0;
            while (__hip_atomic_load(ctr, __ATOMIC_ACQUIRE, __HIP_MEMORY_SCOPE_AGENT) < target) {
                if (++guard > (1 << 22)) { alive = false; break; }
            }
        }
    }
    __syncthreads();
    __threadfence();       // acquire: invalidate L1 so we see other WGs' stores
}

// cooperative projection phase: WG j computes output cols [4j,4j+4) of
// P = act(h @ [Wkr;Wkw;We;Wa].T + b) for ALL 64 batches, plus the 4 scalar
// heads for batch j. h row for batch b is at hbase + b*hstride.
__device__ __forceinline__ void proj_phase(
    int j, int tid, const float* __restrict__ hbase, size_t hstride,
    const float* __restrict__ Wkr, const float* __restrict__ bkr_g,
    const float* __restrict__ Wkw, const float* __restrict__ bkw_g,
    const float* __restrict__ We,  const float* __restrict__ be_g,
    const float* __restrict__ Wa,  const float* __restrict__ ba_g,
    const float* __restrict__ Wbr, const float* __restrict__ bbr_g,
    const float* __restrict__ Wgr, const float* __restrict__ bgr_g,
    const float* __restrict__ Wbw, const float* __restrict__ bbw_g,
    const float* __restrict__ Wgw, const float* __restrict__ bgw_g,
    float* __restrict__ Pbuf)
{
    const int mi = j >> 4;             // source matrix for this WG's 4 cols
    const int rb = (j & 15) * 4;       // row base within that matrix
    const float* Wm = mi == 0 ? Wkr : mi == 1 ? Wkw : mi == 2 ? We : Wa;
    const float* bm = mi == 0 ? bkr_g : mi == 1 ? bkw_g : mi == 2 ? be_g : ba_g;

    const int c  = tid >> 8;           // 0..3 col within group
    const int bb = (tid >> 2) & 63;    // batch
    const int ks = tid & 3;            // k-slice (quad lanes)
    const float* wrow = Wm + (size_t)(rb + c) * H_ + ks * 128;
    const float* hrow = hbase + (size_t)bb * hstride + ks * 128;
    float acc = 0.f;
    #pragma unroll
    for (int i = 0; i < 32; ++i)
        acc += dot4(*(const float4*)&wrow[i * 4], *(const float4*)&hrow[i * 4]);
    acc = red4(acc);
    if (ks == 0) {
        float v = acc + bm[rb + c];
        v = (mi == 2) ? sigmoid_f(v) : tanh_f(v);
        Pbuf[bb * 264 + (j * 4 + c)] = v;
    }

    if (tid >= 960) {   // wave 15 also computes the 4 scalar heads for batch j
        const int lane_ = tid - 960;
        const int hs = lane_ >> 4, s16 = lane_ & 15;
        const float* Wh = hs == 0 ? Wbr : hs == 1 ? Wgr : hs == 2 ? Wbw : Wgw;
        const float bh = (hs == 0 ? bbr_g : hs == 1 ? bgr_g : hs == 2 ? bbw_g : bgw_g)[0];
        const float* hrj = hbase + (size_t)j * hstride + s16 * 32;
        float a2 = 0.f;
        #pragma unroll
        for (int i = 0; i < 8; ++i)
            a2 += dot4(*(const float4*)&hrj[i * 4], *(const float4*)&Wh[s16 * 32 + i * 4]);
        a2 = red16(a2);
        if (s16 == 0) {
            float v = a2 + bh;
            Pbuf[j * 264 + 256 + hs] = (hs & 1) ? sigmoid_f(v) : softplus_f(v);
        }
    }
}

// ---------------- Kernel 2: recurrent loop, one WG per batch + coop proj ----------------
__global__ __launch_bounds__(1024, 4) void ntm_loop(
    const float* __restrict__ xin,
    const float* __restrict__ h0,
    const float* __restrict__ frf0, const float* __restrict__ fwf0,
    const float* __restrict__ m0,
    const float* __restrict__ Wkr, const float* __restrict__ bkr_g,
    const float* __restrict__ Wbr, const float* __restrict__ bbr_g,
    const float* __restrict__ Wgr, const float* __restrict__ bgr_g,
    const float* __restrict__ Wkw, const float* __restrict__ bkw_g,
    const float* __restrict__ Wbw, const float* __restrict__ bbw_g,
    const float* __restrict__ Wgw, const float* __restrict__ bgw_g,
    const float* __restrict__ We,  const float* __restrict__ be_g,
    const float* __restrict__ Wa,  const float* __restrict__ ba_g,
    const float* __restrict__ Wread, const float* __restrict__ bread_g,
    float* __restrict__ h_all, float* __restrict__ Pbuf, unsigned* __restrict__ ctr)
{
    __shared__ __align__(16) float mem[R_ * M_];     // 128 KB
    __shared__ float frf2[2][R_];
    __shared__ float fwf2[2][R_];
    __shared__ float dotsR[R_];
    __shared__ float dotsW[R_];
    __shared__ float nrm2[R_];
    __shared__ float wread_s[R_];
    __shared__ float wwrite_s[R_];
    __shared__ __align__(16) float kR[M_];
    __shared__ __align__(16) float kW[M_];
    __shared__ __align__(16) float eV[M_];
    __shared__ __align__(16) float aV[M_];
    __shared__ __align__(16) float rt[M_];
    __shared__ float dtmp[512];
    __shared__ float wsumR[16], wsumW[16];
    __shared__ float scal[4];   // 0:beta_r 1:g_r 2:beta_w 3:g_w

    const int b    = blockIdx.x;
    const int tid  = threadIdx.x;
    const int wave = tid >> 6, lane = tid & 63;
    const int g    = lane >> 4, sub = lane & 15;
    const int di   = tid & 511, dhalf = tid >> 9;    // phase-D mapping

    // ---- init: stage memory + filters; cache Wread slice in registers ----
    const float* mg = m0 + (size_t)b * (R_ * M_);
    #pragma unroll
    for (int i = 0; i < 8; ++i) {
        int idx = i * 4096 + tid * 4;
        *(float4*)&mem[idx] = *(const float4*)&mg[idx];
    }
    if (tid < R_) { frf2[0][tid] = frf0[b * R_ + tid]; fwf2[0][tid] = fwf0[b * R_ + tid]; }
    float4 wrc[8];
    #pragma unroll
    for (int jj = 0; jj < 8; ++jj)
        wrc[jj] = *(const float4*)&Wread[(size_t)di * M_ + dhalf * 32 + jj * 4];
    const float breg = (dhalf == 0) ? bread_g[di] : 0.f;
    __syncthreads();
    #pragma unroll
    for (int i = 0; i < 8; ++i) {
        int r = wave * 32 + i * 4 + g;
        float4 v = *(float4*)&mem[r * M_ + sub * 4];
        float np = v.x*v.x + v.y*v.y + v.z*v.z + v.w*v.w;
        np = red16(np);
        if (sub == 0) nrm2[r] = np;
    }

    bool alive = true;
    unsigned ep = 0;

    // prologue: P(0) = proj(h0)
    proj_phase(b, tid, h0, (size_t)H_, Wkr, bkr_g, Wkw, bkw_g, We, be_g, Wa, ba_g,
               Wbr, bbr_g, Wgr, bgr_g, Wbw, bbw_g, Wgw, bgw_g, Pbuf);
    gridsync(ctr, NWG * ++ep, alive);

    for (int t = 0; t < T_; ++t) {
        const int cur = t & 1, nxt = cur ^ 1;

        // ---- loop top: read this step's projections; prefetch xin; zero rt ----
        float xin_reg = 0.f;
        if (tid < H_) xin_reg = xin[(size_t)(b * T_ + t) * H_ + tid];
        if (tid < 260) {
            float v = Pbuf[b * 264 + tid];
            if      (tid < 64)  kR[tid] = v;
            else if (tid < 128) kW[tid - 64] = v;
            else if (tid < 192) eV[tid - 128] = v;
            else if (tid < 256) aV[tid - 192] = v;
            else                scal[tid - 256] = v;
        } else if (tid >= 512 && tid < 512 + M_) {
            rt[tid - 512] = 0.f;
        }
        __syncthreads();   // B1

        // ---- Phase B: content dots -> exp scores + per-wave partial sums ----
        {
            float4 kr4 = *(float4*)&kR[sub * 4];
            float4 kw4 = *(float4*)&kW[sub * 4];
            float snKR = sqrtf(red16(dot4(kr4, kr4)));
            float snKW = sqrtf(red16(dot4(kw4, kw4)));
            float beta_r = scal[0], beta_w = scal[2];
            float eaccR = 0.f, eaccW = 0.f;
            #pragma unroll
            for (int i = 0; i < 8; ++i) {
                int r = wave * 32 + i * 4 + g;
                float4 v = *(float4*)&mem[r * M_ + sub * 4];
                float dr = red16(dot4(kr4, v));
                float dw = red16(dot4(kw4, v));
                float sn = sqrtf(nrm2[r]);
                if (sub == 0) {
                    float e = __expf(beta_r * dr / (snKR * sn + EPS_));
                    dotsR[r] = e; eaccR += e;
                } else if (sub == 1) {
                    float e = __expf(beta_w * dw / (snKW * sn + EPS_));
                    dotsW[r] = e; eaccW += e;
                }
            }
            float vR = red16(eaccR); vR += __shfl_xor(vR, 16, 64); vR += __shfl_xor(vR, 32, 64);
            float vW = red16(eaccW); vW += __shfl_xor(vW, 16, 64); vW += __shfl_xor(vW, 32, 64);
            if (lane == 0) { wsumR[wave] = vR; wsumW[wave] = vW; }
        }
        __syncthreads();   // B2

        // ---- Phase C: filters (same-wave) + mem update + r_t partials + norms ----
        {
            if (lane < 32) {
                const int r = wave * 32 + lane;
                float totR = 0, totW = 0;
                #pragma unroll
                for (int w2 = 0; w2 < 16; ++w2) { totR += wsumR[w2]; totW += wsumW[w2]; }
                float invR = 1.f / totR, invW = 1.f / totW;
                const int rm = (r + R_ - 1) & (R_ - 1), rp = (r + 1) & (R_ - 1);
                float gr = scal[1], gw = scal[3];

                float f0 = gr * dotsR[r]  * invR + (1.f - gr) * frf2[cur][r];
                float fm = gr * dotsR[rm] * invR + (1.f - gr) * frf2[cur][rm];
                float fp = gr * dotsR[rp] * invR + (1.f - gr) * frf2[cur][rp];
                frf2[nxt][r] = f0;
                wread_s[r] = 0.5f * f0 + 0.5f * (0.25f * fm + 0.5f * f0 + 0.25f * fp);

                float q0 = gw * dotsW[r]  * invW + (1.f - gw) * fwf2[cur][r];
                float qm = gw * dotsW[rm] * invW + (1.f - gw) * fwf2[cur][rm];
                float qp = gw * dotsW[rp] * invW + (1.f - gw) * fwf2[cur][rp];
                fwf2[nxt][r] = q0;
                wwrite_s[r] = 0.5f * q0 + 0.5f * (0.25f * qm + 0.5f * q0 + 0.25f * qp);
            }
            __builtin_amdgcn_wave_barrier();

            float4 e4 = *(float4*)&eV[sub * 4];
            float4 a4 = *(float4*)&aV[sub * 4];
            float rt0 = 0, rt1 = 0, rt2 = 0, rt3 = 0;
            #pragma unroll
            for (int i = 0; i < 8; ++i) {
                int r = wave * 32 + i * 4 + g;
                float wr = wread_s[r], ww = wwrite_s[r];
                float4 v = *(float4*)&mem[r * M_ + sub * 4];
                rt0 += wr * v.x; rt1 += wr * v.y; rt2 += wr * v.z; rt3 += wr * v.w;
                float4 nv;
                nv.x = v.x * (1.f - ww * e4.x) + ww * a4.x;
                nv.y = v.y * (1.f - ww * e4.y) + ww * a4.y;
                nv.z = v.z * (1.f - ww * e4.z) + ww * a4.z;
                nv.w = v.w * (1.f - ww * e4.w) + ww * a4.w;
                *(float4*)&mem[r * M_ + sub * 4] = nv;
                float np = nv.x*nv.x + nv.y*nv.y + nv.z*nv.z + nv.w*nv.w;
                np = red16(np);
                if (sub == 0) nrm2[r] = np;
            }
            rt0 += __shfl_xor(rt0, 16, 64); rt0 += __shfl_xor(rt0, 32, 64);
            rt1 += __shfl_xor(rt1, 16, 64); rt1 += __shfl_xor(rt1, 32, 64);
            rt2 += __shfl_xor(rt2, 16, 64); rt2 += __shfl_xor(rt2, 32, 64);
            rt3 += __shfl_xor(rt3, 16, 64); rt3 += __shfl_xor(rt3, 32, 64);
            if (g == 0) {
                atomicAdd(&rt[sub * 4 + 0], rt0);
                atomicAdd(&rt[sub * 4 + 1], rt1);
                atomicAdd(&rt[sub * 4 + 2], rt2);
                atomicAdd(&rt[sub * 4 + 3], rt3);
            }
        }
        __syncthreads();   // B3

        // ---- Phase D: h_{t+1} = relu(xin + Wread @ r_t + b_read), Wread in regs ----
        {
            float acc = 0.f;
            #pragma unroll
            for (int jj = 0; jj < 8; ++jj)
                acc += dot4(wrc[jj], *(float4*)&rt[dhalf * 32 + jj * 4]);
            if (dhalf == 1) dtmp[di] = acc;
            __syncthreads();   // B4
            if (dhalf == 0) {
                float hv = fmaxf(xin_reg + acc + dtmp[di] + breg, 0.f);
                h_all[(size_t)(b * T_ + t) * H_ + di] = hv;
            }
        }

        if (t < T_ - 1) {
            gridsync(ctr, NWG * ++ep, alive);   // S1: h(t) visible everywhere
            proj_phase(b, tid, h_all + (size_t)t * H_, (size_t)T_ * H_,
                       Wkr, bkr_g, Wkw, bkw_g, We, be_g, Wa, ba_g,
                       Wbr, bbr_g, Wgr, bgr_g, Wbw, bbw_g, Wgw, bgw_g, Pbuf);
            gridsync(ctr, NWG * ++ep, alive);   // S2: P(t+1) visible everywhere
        }
    }
}

// ---------------- Kernel 3: out = sigmoid(h_all @ W_out.T + b_out) ----------------
__global__ __launch_bounds__(256) void out_gemm(
    const float* __restrict__ h_all, const float* __restrict__ Wout,
    const float* __restrict__ bout, float* __restrict__ out)
{
    __shared__ __align__(16) float hs[32 * H_];
    const int tid  = threadIdx.x;
    const int row0 = blockIdx.x * 32;

    #pragma unroll
    for (int i = 0; i < 16; ++i) {
        int idx = i * 1024 + tid * 4;
        *(float4*)&hs[idx] = *(const float4*)&h_all[(size_t)row0 * H_ + idx];
    }
    __syncthreads();

    const int rg = tid >> 6;
    const int cg = tid & 63;
    const int c0 = cg * 4;
    float acc[8][4];
    #pragma unroll
    for (int r = 0; r < 8; ++r)
        #pragma unroll
        for (int c = 0; c < 4; ++c) acc[r][c] = 0.f;

    for (int k = 0; k < H_; k += 4) {
        float4 xq[8];
        #pragma unroll
        for (int r = 0; r < 8; ++r) xq[r] = *(float4*)&hs[(rg * 8 + r) * H_ + k];
        #pragma unroll
        for (int c = 0; c < 4; ++c) {
            float4 w4 = *(const float4*)&Wout[(size_t)(c0 + c) * H_ + k];
            #pragma unroll
            for (int r = 0; r < 8; ++r) acc[r][c] += dot4(xq[r], w4);
        }
    }
    #pragma unroll
    for (int r = 0; r < 8; ++r) {
        int grow = row0 + rg * 8 + r;
        float4 o4;
        o4.x = sigmoid_f(acc[r][0] + bout[c0 + 0]);
        o4.y = sigmoid_f(acc[r][1] + bout[c0 + 1]);
        o4.z = sigmoid_f(acc[r][2] + bout[c0 + 2]);
        o4.w = sigmoid_f(acc[r][3] + bout[c0 + 3]);
        *(float4*)&out[(size_t)grow * O_ + c0] = o4;
    }
}

extern "C" void kernel_launch(void* const* d_in, const int* in_sizes, int n_in,
                              void* d_out, int out_size, void* d_ws, size_t ws_size,
                              hipStream_t stream) {
    const float* x     = (const float*)d_in[0];
    const float* h0    = (const float*)d_in[1];
    const float* frf   = (const float*)d_in[2];
    const float* fwf   = (const float*)d_in[4];
    const float* m0    = (const float*)d_in[6];
    const float* Win   = (const float*)d_in[7];
    const float* bin   = (const float*)d_in[8];
    const float* Wread = (const float*)d_in[9];
    const float* bread = (const float*)d_in[10];
    const float* Wout  = (const float*)d_in[11];
    const float* bout  = (const float*)d_in[12];
    const float* Wkr   = (const float*)d_in[13];
    const float* bkr   = (const float*)d_in[14];
    const float* Wbr   = (const float*)d_in[15];
    const float* bbr   = (const float*)d_in[16];
    const float* Wgr   = (const float*)d_in[17];
    const float* bgr   = (const float*)d_in[18];
    const float* Wkw   = (const float*)d_in[19];
    const float* bkw   = (const float*)d_in[20];
    const float* Wbw   = (const float*)d_in[21];
    const float* bbw   = (const float*)d_in[22];
    const float* Wgw   = (const float*)d_in[23];
    const float* bgw   = (const float*)d_in[24];
    const float* We    = (const float*)d_in[25];
    const float* be    = (const float*)d_in[26];
    const float* Wa    = (const float*)d_in[27];
    const float* ba    = (const float*)d_in[28];

    float* xin   = (float*)d_ws;                                      // 16 MB
    float* h_all = (float*)((char*)d_ws + (size_t)B_ * T_ * H_ * 4);  // 16 MB
    // sync counter + P buffer live in d_out's head; out_gemm overwrites all of
    // d_out at the end, so this is pure scratch until then.
    unsigned* ctr  = (unsigned*)d_out;
    float*    Pbuf = (float*)((char*)d_out + 256);                    // 64*264*4 = 67.6 KB

    hipMemsetAsync(d_out, 0, 256, stream);
    xin_gemm<<<256, 256, 0, stream>>>(x, Win, bin, xin);
    ntm_loop<<<NWG, 1024, 0, stream>>>(xin, h0, frf, fwf, m0,
        Wkr, bkr, Wbr, bbr, Wgr, bgr, Wkw, bkw, Wbw, bbw, Wgw, bgw,
        We, be, Wa, ba, Wread, bread, h_all, Pbuf, ctr);
    out_gemm<<<256, 256, 0, stream>>>(h_all, Wout, bout, (float*)d_out);
}

// Round 4
// 2269.312 us; speedup vs baseline: 4.2850x; 4.2850x over previous
//
#include <hip/hip_runtime.h>
#include <math.h>

#define B_   64
#define T_   128
#define NIN  256
#define H_   512
#define O_   256
#define M_   64
#define R_   512
#define EPS_ 1e-8f

typedef _Float16 h2 __attribute__((ext_vector_type(2)));

__device__ __forceinline__ float dot4(float4 a, float4 b) {
    return a.x*b.x + a.y*b.y + a.z*b.z + a.w*b.w;
}

// fp16 dot2 accumulate (v_dot2_f32_f16), bit-pattern operands
__device__ __forceinline__ float fd2(unsigned wu, unsigned hu, float acc) {
#if __has_builtin(__builtin_amdgcn_fdot2)
    return __builtin_amdgcn_fdot2(__builtin_bit_cast(h2, wu),
                                  __builtin_bit_cast(h2, hu), acc, false);
#else
    h2 w = __builtin_bit_cast(h2, wu), h = __builtin_bit_cast(h2, hu);
    return acc + (float)w[0]*(float)h[0] + (float)w[1]*(float)h[1];
#endif
}
#define FD4(W, HX, A) { A = fd2(W.x, HX.x, A); A = fd2(W.y, HX.y, A); \
                        A = fd2(W.z, HX.z, A); A = fd2(W.w, HX.w, A); }

__device__ __forceinline__ unsigned pk16(float a, float b) {
    return __builtin_bit_cast(unsigned, __builtin_amdgcn_cvt_pkrtz(a, b));
}
__device__ __forceinline__ unsigned short bits16(float v) {
    return __builtin_bit_cast(unsigned short, (_Float16)v);
}

template<int CTRL>
__device__ __forceinline__ float dpp_add(float v) {
    int t = __builtin_amdgcn_update_dpp(0, __float_as_int(v), CTRL, 0xF, 0xF, false);
    return v + __int_as_float(t);
}
__device__ __forceinline__ float red16(float v) {
    v = dpp_add<0xB1>(v);    // quad_perm xor1
    v = dpp_add<0x4E>(v);    // quad_perm xor2
    v = dpp_add<0x124>(v);   // row_ror:4
    v = dpp_add<0x128>(v);   // row_ror:8
    return v;
}
__device__ __forceinline__ float red64(float v) {
    v = red16(v);
    v += __shfl_xor(v, 16, 64);
    v += __shfl_xor(v, 32, 64);
    return v;
}
__device__ __forceinline__ float tanh_f(float x)    { float e = __expf(2.f * x); return 1.f - 2.f / (e + 1.f); }
__device__ __forceinline__ float sigmoid_f(float x) { return 1.f / (1.f + __expf(-x)); }
__device__ __forceinline__ float softplus_f(float x){ return x > 20.f ? x : log1pf(__expf(x)); }

// ---------- Kernel 0: fp32 -> fp16 conversion of the 4 projection matrices ----------
__global__ __launch_bounds__(256) void w2h(
    const float* __restrict__ Wkr, const float* __restrict__ Wkw,
    const float* __restrict__ We,  const float* __restrict__ Wa,
    unsigned short* __restrict__ Wh)
{
    const int mi = blockIdx.x >> 5;          // 32 blocks per matrix
    const float* s = mi == 0 ? Wkr : mi == 1 ? Wkw : mi == 2 ? We : Wa;
    const int off = (blockIdx.x & 31) * 1024 + threadIdx.x * 4;
    float4 v = *(const float4*)&s[off];
    ushort4 o;
    o.x = bits16(v.x); o.y = bits16(v.y); o.z = bits16(v.z); o.w = bits16(v.w);
    *(ushort4*)&Wh[mi * 32768 + off] = o;
}

// ---------- Kernel 1: xin_h[bt][i] = fp16(x[bt] @ W_in.T + b_in) ----------
__global__ __launch_bounds__(256) void xin_gemm(
    const float* __restrict__ x, const float* __restrict__ Win,
    const float* __restrict__ bin, unsigned short* __restrict__ xin_h)
{
    __shared__ __align__(16) float xs[32 * NIN];
    const int tid  = threadIdx.x;
    const int row0 = blockIdx.x * 32;

    #pragma unroll
    for (int i = 0; i < 8; ++i) {
        int idx = i * 1024 + tid * 4;
        *(float4*)&xs[idx] = *(const float4*)&x[(size_t)row0 * NIN + idx];
    }
    __syncthreads();

    const int rg = tid >> 6;
    const int cg = tid & 63;
    const int c0 = cg * 8;
    float acc[8][8];
    #pragma unroll
    for (int r = 0; r < 8; ++r)
        #pragma unroll
        for (int c = 0; c < 8; ++c) acc[r][c] = 0.f;

    for (int k = 0; k < NIN; k += 4) {
        float4 xq[8];
        #pragma unroll
        for (int r = 0; r < 8; ++r) xq[r] = *(float4*)&xs[(rg * 8 + r) * NIN + k];
        #pragma unroll
        for (int c = 0; c < 8; ++c) {
            float4 w4 = *(const float4*)&Win[(size_t)(c0 + c) * NIN + k];
            #pragma unroll
            for (int r = 0; r < 8; ++r) acc[r][c] += dot4(xq[r], w4);
        }
    }
    #pragma unroll
    for (int r = 0; r < 8; ++r) {
        int grow = row0 + rg * 8 + r;
        ushort4 o0, o1;
        o0.x = bits16(acc[r][0] + bin[c0 + 0]);
        o0.y = bits16(acc[r][1] + bin[c0 + 1]);
        o0.z = bits16(acc[r][2] + bin[c0 + 2]);
        o0.w = bits16(acc[r][3] + bin[c0 + 3]);
        o1.x = bits16(acc[r][4] + bin[c0 + 4]);
        o1.y = bits16(acc[r][5] + bin[c0 + 5]);
        o1.z = bits16(acc[r][6] + bin[c0 + 6]);
        o1.w = bits16(acc[r][7] + bin[c0 + 7]);
        *(ushort4*)&xin_h[(size_t)grow * H_ + c0]     = o0;
        *(ushort4*)&xin_h[(size_t)grow * H_ + c0 + 4] = o1;
    }
}

// ---------- Kernel 2: recurrent loop, one WG per batch element ----------
__global__ __launch_bounds__(1024, 4) void ntm_loop(
    const unsigned short* __restrict__ xin_h,
    const float* __restrict__ h0,
    const float* __restrict__ frf0, const float* __restrict__ fwf0,
    const float* __restrict__ m0,
    const unsigned short* __restrict__ Wh,      // fp16 [Wkr;Wkw;We;Wa]
    const float* __restrict__ bkr_g, const float* __restrict__ bkw_g,
    const float* __restrict__ be_g,  const float* __restrict__ ba_g,
    const float* __restrict__ Wbr, const float* __restrict__ bbr_g,
    const float* __restrict__ Wgr, const float* __restrict__ bgr_g,
    const float* __restrict__ Wbw, const float* __restrict__ bbw_g,
    const float* __restrict__ Wgw, const float* __restrict__ bgw_g,
    const float* __restrict__ Wread, const float* __restrict__ bread_g,
    float* __restrict__ h_all)
{
    __shared__ __align__(16) unsigned short hh[H_];   // fp16 h
    __shared__ __align__(16) float hbuf[H_];          // fp32 h
    __shared__ float frf2[2][R_];
    __shared__ float fwf2[2][R_];
    __shared__ float dotsR[R_];
    __shared__ float dotsW[R_];
    __shared__ float nrm2[R_];
    __shared__ float wread_s[R_];
    __shared__ float wwrite_s[R_];
    __shared__ __align__(16) float kR[M_];
    __shared__ __align__(16) float kW[M_];
    __shared__ __align__(16) float eV[M_];
    __shared__ __align__(16) float aV[M_];
    __shared__ __align__(16) float rt[M_];
    __shared__ __align__(16) float Whead[4 * H_];     // 8 KB: Wbr,Wgr,Wbw,Wgw
    __shared__ float wsumR[16], wsumW[16];
    __shared__ float bias4[4 * M_];
    __shared__ float bhead[4];
    __shared__ float scal[4];   // 0:beta_r 1:g_r 2:beta_w 3:g_w

    const int b    = blockIdx.x;
    const int tid  = threadIdx.x;
    const int wave = tid >> 6, lane = tid & 63;
    const int g    = lane >> 4, sub = lane & 15;
    const int nidx = wave * 32 + (lane & 31);   // phase-D neuron
    const int dhalf = lane >> 5;

    // ---- init ----
    const float* mg = m0 + (size_t)b * (R_ * M_);
    float4 mreg[8];                             // register-resident memory rows
    #pragma unroll
    for (int i = 0; i < 8; ++i)
        mreg[i] = *(const float4*)&mg[(wave * 32 + i * 4 + g) * M_ + sub * 4];

    if (tid < H_) { float hv = h0[b * H_ + tid]; hbuf[tid] = hv; hh[tid] = bits16(hv); }
    if (tid < R_) { frf2[0][tid] = frf0[b * R_ + tid]; fwf2[0][tid] = fwf0[b * R_ + tid]; }
    if (tid < M_) {
        bias4[tid]          = bkr_g[tid];
        bias4[M_ + tid]     = bkw_g[tid];
        bias4[2 * M_ + tid] = be_g[tid];
        bias4[3 * M_ + tid] = ba_g[tid];
    }
    #pragma unroll
    for (int k2 = 0; k2 < 2; ++k2) {
        int idx = k2 * 1024 + tid;
        int mi = idx >> 9;
        const float* src = mi == 0 ? Wbr : mi == 1 ? Wgr : mi == 2 ? Wbw : Wgw;
        Whead[idx] = src[idx & (H_ - 1)];
    }
    if (tid < 4) bhead[tid] = (tid == 0 ? bbr_g : tid == 1 ? bgr_g : tid == 2 ? bbw_g : bgw_g)[0];

    // Wread slice (fp16) in registers: neuron nidx, half dhalf
    unsigned wrch[16];
    {
        const float* wrp = Wread + (size_t)nidx * M_ + dhalf * 32;
        #pragma unroll
        for (int jj = 0; jj < 8; ++jj) {
            float4 w4 = *(const float4*)&wrp[jj * 4];
            wrch[2 * jj]     = pk16(w4.x, w4.y);
            wrch[2 * jj + 1] = pk16(w4.z, w4.w);
        }
    }
    const float breg = (dhalf == 0) ? bread_g[nidx] : 0.f;

    // initial row norms from registers
    #pragma unroll
    for (int i = 0; i < 8; ++i) {
        float4 v = mreg[i];
        float np = red16(v.x*v.x + v.y*v.y + v.z*v.z + v.w*v.w);
        if (sub == 0) nrm2[wave * 32 + i * 4 + g] = np;
    }
    __syncthreads();

    for (int t = 0; t < T_; ++t) {
        const int cur = t & 1, nxt = cur ^ 1;

        // ---- Phase A: projections (fp16 dot2) + scalar heads + prefetch ----
        unsigned short xbits = 0;
        if (dhalf == 0) xbits = xin_h[(size_t)(b * T_ + t) * H_ + nidx];
        if (wave == 15) rt[lane] = 0.f;
        {
            const int row = tid >> 4, s16 = tid & 15;
            const unsigned short* wp = Wh + (size_t)row * H_ + s16 * 8;
            float a0 = 0, a1 = 0, a2 = 0, a3 = 0;
            #pragma unroll
            for (int j = 0; j < 4; ++j) {
                uint4 hx = *(const uint4*)((const char*)hh + j * 256 + s16 * 16);
                uint4 w0 = *(const uint4*)(wp + j * 128);
                uint4 w1 = *(const uint4*)(wp + 32768 + j * 128);
                uint4 w2 = *(const uint4*)(wp + 65536 + j * 128);
                uint4 w3 = *(const uint4*)(wp + 98304 + j * 128);
                FD4(w0, hx, a0); FD4(w1, hx, a1); FD4(w2, hx, a2); FD4(w3, hx, a3);
            }
            a0 = red16(a0); a1 = red16(a1); a2 = red16(a2); a3 = red16(a3);
            if      (s16 == 0) kR[row] = tanh_f(a0 + bias4[row]);
            else if (s16 == 1) kW[row] = tanh_f(a1 + bias4[M_ + row]);
            else if (s16 == 2) eV[row] = sigmoid_f(a2 + bias4[2 * M_ + row]);
            else if (s16 == 3) aV[row] = tanh_f(a3 + bias4[3 * M_ + row]);

            if (tid < 256) {   // 4 scalar heads from LDS weights
                const int sc = tid >> 6;
                const float* Wp = &Whead[sc * H_ + lane * 8];
                float acc = dot4(*(float4*)&hbuf[lane * 8],     *(const float4*)&Wp[0])
                          + dot4(*(float4*)&hbuf[lane * 8 + 4], *(const float4*)&Wp[4]);
                acc = red64(acc);
                if (lane == 0) {
                    float xv = acc + bhead[sc];
                    scal[sc] = (sc & 1) ? sigmoid_f(xv) : softplus_f(xv);
                }
            }
        }
        __syncthreads();   // B1

        // ---- Phase B: content dots (register mem) -> exp scores + partial sums ----
        {
            float4 kr4 = *(float4*)&kR[sub * 4];
            float4 kw4 = *(float4*)&kW[sub * 4];
            float snKR = sqrtf(red16(dot4(kr4, kr4)));
            float snKW = sqrtf(red16(dot4(kw4, kw4)));
            float beta_r = scal[0], beta_w = scal[2];
            float eaccR = 0.f, eaccW = 0.f;
            #pragma unroll
            for (int i = 0; i < 8; ++i) {
                int r = wave * 32 + i * 4 + g;
                float4 v = mreg[i];
                float dr = red16(dot4(kr4, v));
                float dw = red16(dot4(kw4, v));
                float sn = sqrtf(nrm2[r]);
                if (sub == 0) {
                    float e = __expf(beta_r * dr / (snKR * sn + EPS_));
                    dotsR[r] = e; eaccR += e;
                } else if (sub == 1) {
                    float e = __expf(beta_w * dw / (snKW * sn + EPS_));
                    dotsW[r] = e; eaccW += e;
                }
            }
            float vR = red64(eaccR);
            float vW = red64(eaccW);
            if (lane == 0) { wsumR[wave] = vR; wsumW[wave] = vW; }
        }
        __syncthreads();   // B2

        // ---- Phase C: filters + mem update (registers) + r_t partials + norms ----
        {
            if (lane < 32) {
                const int r = wave * 32 + lane;
                float totR = 0, totW = 0;
                #pragma unroll
                for (int w2 = 0; w2 < 16; ++w2) { totR += wsumR[w2]; totW += wsumW[w2]; }
                float invR = 1.f / totR, invW = 1.f / totW;
                const int rm = (r + R_ - 1) & (R_ - 1), rp = (r + 1) & (R_ - 1);
                float gr = scal[1], gw = scal[3];

                float f0 = gr * dotsR[r]  * invR + (1.f - gr) * frf2[cur][r];
                float fm = gr * dotsR[rm] * invR + (1.f - gr) * frf2[cur][rm];
                float fp = gr * dotsR[rp] * invR + (1.f - gr) * frf2[cur][rp];
                frf2[nxt][r] = f0;
                wread_s[r] = 0.5f * f0 + 0.5f * (0.25f * fm + 0.5f * f0 + 0.25f * fp);

                float q0 = gw * dotsW[r]  * invW + (1.f - gw) * fwf2[cur][r];
                float qm = gw * dotsW[rm] * invW + (1.f - gw) * fwf2[cur][rm];
                float qp = gw * dotsW[rp] * invW + (1.f - gw) * fwf2[cur][rp];
                fwf2[nxt][r] = q0;
                wwrite_s[r] = 0.5f * q0 + 0.5f * (0.25f * qm + 0.5f * q0 + 0.25f * qp);
            }
            __builtin_amdgcn_wave_barrier();

            float4 e4 = *(float4*)&eV[sub * 4];
            float4 a4 = *(float4*)&aV[sub * 4];
            float rt0 = 0, rt1 = 0, rt2 = 0, rt3 = 0;
            #pragma unroll
            for (int i = 0; i < 8; ++i) {
                int r = wave * 32 + i * 4 + g;
                float wr = wread_s[r], ww = wwrite_s[r];
                float4 v = mreg[i];
                rt0 += wr * v.x; rt1 += wr * v.y; rt2 += wr * v.z; rt3 += wr * v.w;
                float4 nv;
                nv.x = v.x * (1.f - ww * e4.x) + ww * a4.x;
                nv.y = v.y * (1.f - ww * e4.y) + ww * a4.y;
                nv.z = v.z * (1.f - ww * e4.z) + ww * a4.z;
                nv.w = v.w * (1.f - ww * e4.w) + ww * a4.w;
                mreg[i] = nv;
                float np = red16(nv.x*nv.x + nv.y*nv.y + nv.z*nv.z + nv.w*nv.w);
                if (sub == 0) nrm2[r] = np;
            }
            rt0 += __shfl_xor(rt0, 16, 64); rt0 += __shfl_xor(rt0, 32, 64);
            rt1 += __shfl_xor(rt1, 16, 64); rt1 += __shfl_xor(rt1, 32, 64);
            rt2 += __shfl_xor(rt2, 16, 64); rt2 += __shfl_xor(rt2, 32, 64);
            rt3 += __shfl_xor(rt3, 16, 64); rt3 += __shfl_xor(rt3, 32, 64);
            if (g == 0) {
                atomicAdd(&rt[sub * 4 + 0], rt0);
                atomicAdd(&rt[sub * 4 + 1], rt1);
                atomicAdd(&rt[sub * 4 + 2], rt2);
                atomicAdd(&rt[sub * 4 + 3], rt3);
            }
        }
        __syncthreads();   // B3

        // ---- Phase D: h = relu(xin + Wread @ r_t + b); paired within wave ----
        {
            float acc = 0.f;
            #pragma unroll
            for (int jj = 0; jj < 8; ++jj) {
                float4 r4 = *(float4*)&rt[dhalf * 32 + jj * 4];
                unsigned ra = pk16(r4.x, r4.y), rb = pk16(r4.z, r4.w);
                acc = fd2(wrch[2 * jj], ra, acc);
                acc = fd2(wrch[2 * jj + 1], rb, acc);
            }
            acc += __shfl_xor(acc, 32, 64);
            if (dhalf == 0) {
                float xv = (float)__builtin_bit_cast(_Float16, xbits);
                float hv = fmaxf(xv + acc + breg, 0.f);
                hbuf[nidx] = hv;
                hh[nidx] = bits16(hv);
                h_all[(size_t)(b * T_ + t) * H_ + nidx] = hv;
            }
        }
        __syncthreads();   // B4
    }
}

// ---------- Kernel 3: out = sigmoid(h_all @ W_out.T + b_out) ----------
__global__ __launch_bounds__(256) void out_gemm(
    const float* __restrict__ h_all, const float* __restrict__ Wout,
    const float* __restrict__ bout, float* __restrict__ out)
{
    __shared__ __align__(16) float hs[32 * H_];
    const int tid  = threadIdx.x;
    const int row0 = blockIdx.x * 32;

    #pragma unroll
    for (int i = 0; i < 16; ++i) {
        int idx = i * 1024 + tid * 4;
        *(float4*)&hs[idx] = *(const float4*)&h_all[(size_t)row0 * H_ + idx];
    }
    __syncthreads();

    const int rg = tid >> 6;
    const int cg = tid & 63;
    const int c0 = cg * 4;
    float acc[8][4];
    #pragma unroll
    for (int r = 0; r < 8; ++r)
        #pragma unroll
        for (int c = 0; c < 4; ++c) acc[r][c] = 0.f;

    for (int k = 0; k < H_; k += 4) {
        float4 xq[8];
        #pragma unroll
        for (int r = 0; r < 8; ++r) xq[r] = *(float4*)&hs[(rg * 8 + r) * H_ + k];
        #pragma unroll
        for (int c = 0; c < 4; ++c) {
            float4 w4 = *(const float4*)&Wout[(size_t)(c0 + c) * H_ + k];
            #pragma unroll
            for (int r = 0; r < 8; ++r) acc[r][c] += dot4(xq[r], w4);
        }
    }
    #pragma unroll
    for (int r = 0; r < 8; ++r) {
        int grow = row0 + rg * 8 + r;
        float4 o4;
        o4.x = sigmoid_f(acc[r][0] + bout[c0 + 0]);
        o4.y = sigmoid_f(acc[r][1] + bout[c0 + 1]);
        o4.z = sigmoid_f(acc[r][2] + bout[c0 + 2]);
        o4.w = sigmoid_f(acc[r][3] + bout[c0 + 3]);
        *(float4*)&out[(size_t)grow * O_ + c0] = o4;
    }
}

extern "C" void kernel_launch(void* const* d_in, const int* in_sizes, int n_in,
                              void* d_out, int out_size, void* d_ws, size_t ws_size,
                              hipStream_t stream) {
    const float* x     = (const float*)d_in[0];
    const float* h0    = (const float*)d_in[1];
    const float* frf   = (const float*)d_in[2];
    const float* fwf   = (const float*)d_in[4];
    const float* m0    = (const float*)d_in[6];
    const float* Win   = (const float*)d_in[7];
    const float* bin   = (const float*)d_in[8];
    const float* Wread = (const float*)d_in[9];
    const float* bread = (const float*)d_in[10];
    const float* Wout  = (const float*)d_in[11];
    const float* bout  = (const float*)d_in[12];
    const float* Wkr   = (const float*)d_in[13];
    const float* bkr   = (const float*)d_in[14];
    const float* Wbr   = (const float*)d_in[15];
    const float* bbr   = (const float*)d_in[16];
    const float* Wgr   = (const float*)d_in[17];
    const float* bgr   = (const float*)d_in[18];
    const float* Wkw   = (const float*)d_in[19];
    const float* bkw   = (const float*)d_in[20];
    const float* Wbw   = (const float*)d_in[21];
    const float* bbw   = (const float*)d_in[22];
    const float* Wgw   = (const float*)d_in[23];
    const float* bgw   = (const float*)d_in[24];
    const float* We    = (const float*)d_in[25];
    const float* be    = (const float*)d_in[26];
    const float* Wa    = (const float*)d_in[27];
    const float* ba    = (const float*)d_in[28];

    unsigned short* xin_h = (unsigned short*)d_ws;                              // 8 MB
    float* h_all = (float*)((char*)d_ws + (size_t)B_ * T_ * H_ * 2);            // 16 MB
    unsigned short* Wh = (unsigned short*)((char*)d_ws + (size_t)B_ * T_ * H_ * 6);  // 256 KB

    w2h<<<128, 256, 0, stream>>>(Wkr, Wkw, We, Wa, Wh);
    xin_gemm<<<256, 256, 0, stream>>>(x, Win, bin, xin_h);
    ntm_loop<<<B_, 1024, 0, stream>>>(xin_h, h0, frf, fwf, m0,
        Wh, bkr, bkw, be, ba,
        Wbr, bbr, Wgr, bgr, Wbw, bbw, Wgw, bgw,
        Wread, bread, h_all);
    out_gemm<<<256, 256, 0, stream>>>(h_all, Wout, bout, (float*)d_out);
}

// Round 5
// 2202.278 us; speedup vs baseline: 4.4155x; 1.0304x over previous
//
#include <hip/hip_runtime.h>
#include <math.h>

#define B_   64
#define T_   128
#define NIN  256
#define H_   512
#define O_   256
#define M_   64
#define R_   512
#define EPS_ 1e-8f

typedef _Float16 h2 __attribute__((ext_vector_type(2)));

__device__ __forceinline__ float dot4(float4 a, float4 b) {
    return a.x*b.x + a.y*b.y + a.z*b.z + a.w*b.w;
}

// fp16 dot2 accumulate (v_dot2_f32_f16), bit-pattern operands
__device__ __forceinline__ float fd2(unsigned wu, unsigned hu, float acc) {
#if __has_builtin(__builtin_amdgcn_fdot2)
    return __builtin_amdgcn_fdot2(__builtin_bit_cast(h2, wu),
                                  __builtin_bit_cast(h2, hu), acc, false);
#else
    h2 w = __builtin_bit_cast(h2, wu), h = __builtin_bit_cast(h2, hu);
    return acc + (float)w[0]*(float)h[0] + (float)w[1]*(float)h[1];
#endif
}
#define FD4(W, HX, A) { A = fd2(W.x, HX.x, A); A = fd2(W.y, HX.y, A); \
                        A = fd2(W.z, HX.z, A); A = fd2(W.w, HX.w, A); }

__device__ __forceinline__ unsigned pk16(float a, float b) {
    return __builtin_bit_cast(unsigned, __builtin_amdgcn_cvt_pkrtz(a, b));
}
__device__ __forceinline__ unsigned short bits16(float v) {
    return __builtin_bit_cast(unsigned short, (_Float16)v);
}

template<int CTRL>
__device__ __forceinline__ float dpp_add(float v) {
    int t = __builtin_amdgcn_update_dpp(0, __float_as_int(v), CTRL, 0xF, 0xF, false);
    return v + __int_as_float(t);
}
__device__ __forceinline__ float red16(float v) {
    v = dpp_add<0xB1>(v);    // quad_perm xor1
    v = dpp_add<0x4E>(v);    // quad_perm xor2
    v = dpp_add<0x124>(v);   // row_ror:4
    v = dpp_add<0x128>(v);   // row_ror:8
    return v;
}
__device__ __forceinline__ float red64(float v) {
    v = red16(v);
    v += __shfl_xor(v, 16, 64);
    v += __shfl_xor(v, 32, 64);
    return v;
}
__device__ __forceinline__ float tanh_f(float x)    { float e = __expf(2.f * x); return 1.f - 2.f / (e + 1.f); }
__device__ __forceinline__ float sigmoid_f(float x) { return 1.f / (1.f + __expf(-x)); }
__device__ __forceinline__ float softplus_f(float x){ return x > 20.f ? x : log1pf(__expf(x)); }

// ---------- Kernel 0: fp32 -> fp16 conversion of the 4 projection matrices ----------
__global__ __launch_bounds__(256) void w2h(
    const float* __restrict__ Wkr, const float* __restrict__ Wkw,
    const float* __restrict__ We,  const float* __restrict__ Wa,
    unsigned short* __restrict__ Wh)
{
    const int mi = blockIdx.x >> 5;          // 32 blocks per matrix
    const float* s = mi == 0 ? Wkr : mi == 1 ? Wkw : mi == 2 ? We : Wa;
    const int off = (blockIdx.x & 31) * 1024 + threadIdx.x * 4;
    float4 v = *(const float4*)&s[off];
    ushort4 o;
    o.x = bits16(v.x); o.y = bits16(v.y); o.z = bits16(v.z); o.w = bits16(v.w);
    *(ushort4*)&Wh[mi * 32768 + off] = o;
}

// ---------- Kernel 1: xin_h[bt][i] = fp16(x[bt] @ W_in.T + b_in) ----------
__global__ __launch_bounds__(256) void xin_gemm(
    const float* __restrict__ x, const float* __restrict__ Win,
    const float* __restrict__ bin, unsigned short* __restrict__ xin_h)
{
    __shared__ __align__(16) float xs[32 * NIN];
    const int tid  = threadIdx.x;
    const int row0 = blockIdx.x * 32;

    #pragma unroll
    for (int i = 0; i < 8; ++i) {
        int idx = i * 1024 + tid * 4;
        *(float4*)&xs[idx] = *(const float4*)&x[(size_t)row0 * NIN + idx];
    }
    __syncthreads();

    const int rg = tid >> 6;
    const int cg = tid & 63;
    const int c0 = cg * 8;
    float acc[8][8];
    #pragma unroll
    for (int r = 0; r < 8; ++r)
        #pragma unroll
        for (int c = 0; c < 8; ++c) acc[r][c] = 0.f;

    for (int k = 0; k < NIN; k += 4) {
        float4 xq[8];
        #pragma unroll
        for (int r = 0; r < 8; ++r) xq[r] = *(float4*)&xs[(rg * 8 + r) * NIN + k];
        #pragma unroll
        for (int c = 0; c < 8; ++c) {
            float4 w4 = *(const float4*)&Win[(size_t)(c0 + c) * NIN + k];
            #pragma unroll
            for (int r = 0; r < 8; ++r) acc[r][c] += dot4(xq[r], w4);
        }
    }
    #pragma unroll
    for (int r = 0; r < 8; ++r) {
        int grow = row0 + rg * 8 + r;
        ushort4 o0, o1;
        o0.x = bits16(acc[r][0] + bin[c0 + 0]);
        o0.y = bits16(acc[r][1] + bin[c0 + 1]);
        o0.z = bits16(acc[r][2] + bin[c0 + 2]);
        o0.w = bits16(acc[r][3] + bin[c0 + 3]);
        o1.x = bits16(acc[r][4] + bin[c0 + 4]);
        o1.y = bits16(acc[r][5] + bin[c0 + 5]);
        o1.z = bits16(acc[r][6] + bin[c0 + 6]);
        o1.w = bits16(acc[r][7] + bin[c0 + 7]);
        *(ushort4*)&xin_h[(size_t)grow * H_ + c0]     = o0;
        *(ushort4*)&xin_h[(size_t)grow * H_ + c0 + 4] = o1;
    }
}

// ---------- Kernel 2: recurrent loop, one WG per batch element ----------
__global__ __launch_bounds__(1024, 4) void ntm_loop(
    const unsigned short* __restrict__ xin_h,
    const float* __restrict__ h0,
    const float* __restrict__ frf0, const float* __restrict__ fwf0,
    const float* __restrict__ m0,
    const unsigned short* __restrict__ Wh,      // fp16 [Wkr;Wkw;We;Wa]
    const float* __restrict__ bkr_g, const float* __restrict__ bkw_g,
    const float* __restrict__ be_g,  const float* __restrict__ ba_g,
    const float* __restrict__ Wbr, const float* __restrict__ bbr_g,
    const float* __restrict__ Wgr, const float* __restrict__ bgr_g,
    const float* __restrict__ Wbw, const float* __restrict__ bbw_g,
    const float* __restrict__ Wgw, const float* __restrict__ bgw_g,
    const float* __restrict__ Wread, const float* __restrict__ bread_g,
    float* __restrict__ h_all)
{
    __shared__ __align__(16) unsigned short hh[H_];   // fp16 h (1 KB)
    __shared__ __align__(16) float hbuf[H_];          // fp32 h (2 KB)
    __shared__ __align__(16) unsigned wrh[16384];     // fp16 Wread, swizzled (64 KB)
    __shared__ float frf2[2][R_];
    __shared__ float fwf2[2][R_];
    __shared__ float dotsR[R_];
    __shared__ float dotsW[R_];
    __shared__ float nrm2[R_];
    __shared__ float wread_s[R_];
    __shared__ float wwrite_s[R_];
    __shared__ __align__(16) float kR[M_];
    __shared__ __align__(16) float kW[M_];
    __shared__ __align__(16) float eV[M_];
    __shared__ __align__(16) float aV[M_];
    __shared__ __align__(16) float rt[M_];
    __shared__ __align__(16) float Whead[4 * H_];     // 8 KB: Wbr,Wgr,Wbw,Wgw
    __shared__ float wsumR[16], wsumW[16];
    __shared__ float bias4[4 * M_];
    __shared__ float bhead[4];
    __shared__ float scal[4];   // 0:beta_r 1:g_r 2:beta_w 3:g_w

    const int b    = blockIdx.x;
    const int tid  = threadIdx.x;
    const int wave = tid >> 6, lane = tid & 63;
    const int g    = lane >> 4, sub = lane & 15;
    const int nidx = wave * 32 + (lane & 31);   // phase-D neuron
    const int dhalf = lane >> 5;
    const int row = tid >> 4, s16 = tid & 15;   // phase-A mapping

    // ---- init ----
    const float* mg = m0 + (size_t)b * (R_ * M_);
    float4 mreg[8];                             // register-resident memory rows (32 VGPR)
    #pragma unroll
    for (int i = 0; i < 8; ++i)
        mreg[i] = *(const float4*)&mg[(wave * 32 + i * 4 + g) * M_ + sub * 4];

    // register-resident projection weights: 4 matrices x 32 fp16 = 64 VGPR
    uint4 w16[16];   // [m*4+j]
    #pragma unroll
    for (int m = 0; m < 4; ++m)
        #pragma unroll
        for (int j = 0; j < 4; ++j)
            w16[m * 4 + j] = *(const uint4*)&Wh[m * 32768 + row * H_ + s16 * 32 + j * 8];

    if (tid < H_) { float hv = h0[b * H_ + tid]; hbuf[tid] = hv; hh[tid] = bits16(hv); }
    if (tid < R_) { frf2[0][tid] = frf0[b * R_ + tid]; fwf2[0][tid] = fwf0[b * R_ + tid]; }
    if (tid < M_) {
        bias4[tid]          = bkr_g[tid];
        bias4[M_ + tid]     = bkw_g[tid];
        bias4[2 * M_ + tid] = be_g[tid];
        bias4[3 * M_ + tid] = ba_g[tid];
    }
    #pragma unroll
    for (int k2 = 0; k2 < 2; ++k2) {
        int idx = k2 * 1024 + tid;
        int mi = idx >> 9;
        const float* src = mi == 0 ? Wbr : mi == 1 ? Wgr : mi == 2 ? Wbw : Wgw;
        Whead[idx] = src[idx & (H_ - 1)];
    }
    if (tid < 4) bhead[tid] = (tid == 0 ? bbr_g : tid == 1 ? bgr_g : tid == 2 ? bbw_g : bgw_g)[0];

    // Wread -> LDS fp16, 4-dword-chunk XOR swizzle (read: 4-way conflict, ~free)
    {
        const int wn = tid >> 1, wd = tid & 1;      // neuron, half
        const float* wrp = Wread + (size_t)wn * M_ + wd * 32;
        #pragma unroll
        for (int c = 0; c < 4; ++c) {
            float4 wa = *(const float4*)&wrp[c * 8];
            float4 wb = *(const float4*)&wrp[c * 8 + 4];
            uint4 o;
            o.x = pk16(wa.x, wa.y); o.y = pk16(wa.z, wa.w);
            o.z = pk16(wb.x, wb.y); o.w = pk16(wb.z, wb.w);
            *(uint4*)&wrh[wn * 32 + wd * 16 + ((c ^ (wn & 3)) << 2)] = o;
        }
    }
    const float breg = (dhalf == 0) ? bread_g[nidx] : 0.f;

    // initial row norms from registers
    #pragma unroll
    for (int i = 0; i < 8; ++i) {
        float4 v = mreg[i];
        float np = red16(v.x*v.x + v.y*v.y + v.z*v.z + v.w*v.w);
        if (sub == 0) nrm2[wave * 32 + i * 4 + g] = np;
    }
    __syncthreads();

    for (int t = 0; t < T_; ++t) {
        const int cur = t & 1, nxt = cur ^ 1;

        // ---- Phase A: projections (register weights, fp16 dot2) + scalar heads ----
        unsigned short xbits = 0;
        if (dhalf == 0) xbits = xin_h[(size_t)(b * T_ + t) * H_ + nidx];
        if (wave == 15) rt[lane] = 0.f;
        {
            float a0 = 0, a1 = 0, a2 = 0, a3 = 0;
            #pragma unroll
            for (int j = 0; j < 4; ++j) {
                uint4 hx = *(const uint4*)&hh[s16 * 32 + j * 8];
                FD4(w16[0 * 4 + j], hx, a0);
                FD4(w16[1 * 4 + j], hx, a1);
                FD4(w16[2 * 4 + j], hx, a2);
                FD4(w16[3 * 4 + j], hx, a3);
            }
            a0 = red16(a0); a1 = red16(a1); a2 = red16(a2); a3 = red16(a3);
            if      (s16 == 0) kR[row] = tanh_f(a0 + bias4[row]);
            else if (s16 == 1) kW[row] = tanh_f(a1 + bias4[M_ + row]);
            else if (s16 == 2) eV[row] = sigmoid_f(a2 + bias4[2 * M_ + row]);
            else if (s16 == 3) aV[row] = tanh_f(a3 + bias4[3 * M_ + row]);

            if (tid < 256) {   // 4 scalar heads from LDS weights
                const int sc = tid >> 6;
                const float* Wp = &Whead[sc * H_ + lane * 8];
                float acc = dot4(*(float4*)&hbuf[lane * 8],     *(const float4*)&Wp[0])
                          + dot4(*(float4*)&hbuf[lane * 8 + 4], *(const float4*)&Wp[4]);
                acc = red64(acc);
                if (lane == 0) {
                    float xv = acc + bhead[sc];
                    scal[sc] = (sc & 1) ? sigmoid_f(xv) : softplus_f(xv);
                }
            }
        }
        __syncthreads();   // B1

        // ---- Phase B: content dots (register mem) -> exp scores + partial sums ----
        {
            float4 kr4 = *(float4*)&kR[sub * 4];
            float4 kw4 = *(float4*)&kW[sub * 4];
            float snKR = sqrtf(red16(dot4(kr4, kr4)));
            float snKW = sqrtf(red16(dot4(kw4, kw4)));
            float beta_r = scal[0], beta_w = scal[2];
            float eaccR = 0.f, eaccW = 0.f;
            #pragma unroll
            for (int i = 0; i < 8; ++i) {
                int r = wave * 32 + i * 4 + g;
                float4 v = mreg[i];
                float dr = red16(dot4(kr4, v));
                float dw = red16(dot4(kw4, v));
                float sn = sqrtf(nrm2[r]);
                if (sub == 0) {
                    float e = __expf(beta_r * dr / (snKR * sn + EPS_));
                    dotsR[r] = e; eaccR += e;
                } else if (sub == 1) {
                    float e = __expf(beta_w * dw / (snKW * sn + EPS_));
                    dotsW[r] = e; eaccW += e;
                }
            }
            float vR = red64(eaccR);
            float vW = red64(eaccW);
            if (lane == 0) { wsumR[wave] = vR; wsumW[wave] = vW; }
        }
        __syncthreads();   // B2

        // ---- Phase C: filters + mem update (registers) + r_t partials + norms ----
        {
            if (lane < 32) {
                const int r = wave * 32 + lane;
                float totR = 0, totW = 0;
                #pragma unroll
                for (int w2 = 0; w2 < 16; ++w2) { totR += wsumR[w2]; totW += wsumW[w2]; }
                float invR = 1.f / totR, invW = 1.f / totW;
                const int rm = (r + R_ - 1) & (R_ - 1), rp = (r + 1) & (R_ - 1);
                float gr = scal[1], gw = scal[3];

                float f0 = gr * dotsR[r]  * invR + (1.f - gr) * frf2[cur][r];
                float fm = gr * dotsR[rm] * invR + (1.f - gr) * frf2[cur][rm];
                float fp = gr * dotsR[rp] * invR + (1.f - gr) * frf2[cur][rp];
                frf2[nxt][r] = f0;
                wread_s[r] = 0.5f * f0 + 0.5f * (0.25f * fm + 0.5f * f0 + 0.25f * fp);

                float q0 = gw * dotsW[r]  * invW + (1.f - gw) * fwf2[cur][r];
                float qm = gw * dotsW[rm] * invW + (1.f - gw) * fwf2[cur][rm];
                float qp = gw * dotsW[rp] * invW + (1.f - gw) * fwf2[cur][rp];
                fwf2[nxt][r] = q0;
                wwrite_s[r] = 0.5f * q0 + 0.5f * (0.25f * qm + 0.5f * q0 + 0.25f * qp);
            }
            __builtin_amdgcn_wave_barrier();

            float4 e4 = *(float4*)&eV[sub * 4];
            float4 a4 = *(float4*)&aV[sub * 4];
            float rt0 = 0, rt1 = 0, rt2 = 0, rt3 = 0;
            #pragma unroll
            for (int i = 0; i < 8; ++i) {
                int r = wave * 32 + i * 4 + g;
                float wr = wread_s[r], ww = wwrite_s[r];
                float4 v = mreg[i];
                rt0 += wr * v.x; rt1 += wr * v.y; rt2 += wr * v.z; rt3 += wr * v.w;
                float4 nv;
                nv.x = v.x * (1.f - ww * e4.x) + ww * a4.x;
                nv.y = v.y * (1.f - ww * e4.y) + ww * a4.y;
                nv.z = v.z * (1.f - ww * e4.z) + ww * a4.z;
                nv.w = v.w * (1.f - ww * e4.w) + ww * a4.w;
                mreg[i] = nv;
                float np = red16(nv.x*nv.x + nv.y*nv.y + nv.z*nv.z + nv.w*nv.w);
                if (sub == 0) nrm2[r] = np;
            }
            rt0 += __shfl_xor(rt0, 16, 64); rt0 += __shfl_xor(rt0, 32, 64);
            rt1 += __shfl_xor(rt1, 16, 64); rt1 += __shfl_xor(rt1, 32, 64);
            rt2 += __shfl_xor(rt2, 16, 64); rt2 += __shfl_xor(rt2, 32, 64);
            rt3 += __shfl_xor(rt3, 16, 64); rt3 += __shfl_xor(rt3, 32, 64);
            if (g == 0) {
                atomicAdd(&rt[sub * 4 + 0], rt0);
                atomicAdd(&rt[sub * 4 + 1], rt1);
                atomicAdd(&rt[sub * 4 + 2], rt2);
                atomicAdd(&rt[sub * 4 + 3], rt3);
            }
        }
        __syncthreads();   // B3

        // ---- Phase D: h = relu(xin + Wread @ r_t + b); Wread from swizzled LDS ----
        {
            const int base = nidx * 32 + dhalf * 16;
            const int swz  = nidx & 3;
            float acc = 0.f;
            #pragma unroll
            for (int c = 0; c < 4; ++c) {
                uint4 wq = *(uint4*)&wrh[base + ((c ^ swz) << 2)];
                float4 ra = *(float4*)&rt[dhalf * 32 + c * 8];
                float4 rb = *(float4*)&rt[dhalf * 32 + c * 8 + 4];
                unsigned p0 = pk16(ra.x, ra.y), p1 = pk16(ra.z, ra.w);
                unsigned p2 = pk16(rb.x, rb.y), p3 = pk16(rb.z, rb.w);
                acc = fd2(wq.x, p0, acc); acc = fd2(wq.y, p1, acc);
                acc = fd2(wq.z, p2, acc); acc = fd2(wq.w, p3, acc);
            }
            acc += __shfl_xor(acc, 32, 64);
            if (dhalf == 0) {
                float xv = (float)__builtin_bit_cast(_Float16, xbits);
                float hv = fmaxf(xv + acc + breg, 0.f);
                hbuf[nidx] = hv;
                hh[nidx] = bits16(hv);
                h_all[(size_t)(b * T_ + t) * H_ + nidx] = hv;
            }
        }
        __syncthreads();   // B4
    }
}

// ---------- Kernel 3: out = sigmoid(h_all @ W_out.T + b_out) ----------
__global__ __launch_bounds__(256) void out_gemm(
    const float* __restrict__ h_all, const float* __restrict__ Wout,
    const float* __restrict__ bout, float* __restrict__ out)
{
    __shared__ __align__(16) float hs[32 * H_];
    const int tid  = threadIdx.x;
    const int row0 = blockIdx.x * 32;

    #pragma unroll
    for (int i = 0; i < 16; ++i) {
        int idx = i * 1024 + tid * 4;
        *(float4*)&hs[idx] = *(const float4*)&h_all[(size_t)row0 * H_ + idx];
    }
    __syncthreads();

    const int rg = tid >> 6;
    const int cg = tid & 63;
    const int c0 = cg * 4;
    float acc[8][4];
    #pragma unroll
    for (int r = 0; r < 8; ++r)
        #pragma unroll
        for (int c = 0; c < 4; ++c) acc[r][c] = 0.f;

    for (int k = 0; k < H_; k += 4) {
        float4 xq[8];
        #pragma unroll
        for (int r = 0; r < 8; ++r) xq[r] = *(float4*)&hs[(rg * 8 + r) * H_ + k];
        #pragma unroll
        for (int c = 0; c < 4; ++c) {
            float4 w4 = *(const float4*)&Wout[(size_t)(c0 + c) * H_ + k];
            #pragma unroll
            for (int r = 0; r < 8; ++r) acc[r][c] += dot4(xq[r], w4);
        }
    }
    #pragma unroll
    for (int r = 0; r < 8; ++r) {
        int grow = row0 + rg * 8 + r;
        float4 o4;
        o4.x = sigmoid_f(acc[r][0] + bout[c0 + 0]);
        o4.y = sigmoid_f(acc[r][1] + bout[c0 + 1]);
        o4.z = sigmoid_f(acc[r][2] + bout[c0 + 2]);
        o4.w = sigmoid_f(acc[r][3] + bout[c0 + 3]);
        *(float4*)&out[(size_t)grow * O_ + c0] = o4;
    }
}

extern "C" void kernel_launch(void* const* d_in, const int* in_sizes, int n_in,
                              void* d_out, int out_size, void* d_ws, size_t ws_size,
                              hipStream_t stream) {
    const float* x     = (const float*)d_in[0];
    const float* h0    = (const float*)d_in[1];
    const float* frf   = (const float*)d_in[2];
    const float* fwf   = (const float*)d_in[4];
    const float* m0    = (const float*)d_in[6];
    const float* Win   = (const float*)d_in[7];
    const float* bin   = (const float*)d_in[8];
    const float* Wread = (const float*)d_in[9];
    const float* bread = (const float*)d_in[10];
    const float* Wout  = (const float*)d_in[11];
    const float* bout  = (const float*)d_in[12];
    const float* Wkr   = (const float*)d_in[13];
    const float* bkr   = (const float*)d_in[14];
    const float* Wbr   = (const float*)d_in[15];
    const float* bbr   = (const float*)d_in[16];
    const float* Wgr   = (const float*)d_in[17];
    const float* bgr   = (const float*)d_in[18];
    const float* Wkw   = (const float*)d_in[19];
    const float* bkw   = (const float*)d_in[20];
    const float* Wbw   = (const float*)d_in[21];
    const float* bbw   = (const float*)d_in[22];
    const float* Wgw   = (const float*)d_in[23];
    const float* bgw   = (const float*)d_in[24];
    const float* We    = (const float*)d_in[25];
    const float* be    = (const float*)d_in[26];
    const float* Wa    = (const float*)d_in[27];
    const float* ba    = (const float*)d_in[28];

    unsigned short* xin_h = (unsigned short*)d_ws;                              // 8 MB
    float* h_all = (float*)((char*)d_ws + (size_t)B_ * T_ * H_ * 2);            // 16 MB
    unsigned short* Wh = (unsigned short*)((char*)d_ws + (size_t)B_ * T_ * H_ * 6);  // 256 KB

    w2h<<<128, 256, 0, stream>>>(Wkr, Wkw, We, Wa, Wh);
    xin_gemm<<<256, 256, 0, stream>>>(x, Win, bin, xin_h);
    ntm_loop<<<B_, 1024, 0, stream>>>(xin_h, h0, frf, fwf, m0,
        Wh, bkr, bkw, be, ba,
        Wbr, bbr, Wgr, bgr, Wbw, bbw, Wgw, bgw,
        Wread, bread, h_all);
    out_gemm<<<256, 256, 0, stream>>>(h_all, Wout, bout, (float*)d_out);
}

// Round 6
// 1900.440 us; speedup vs baseline: 5.1168x; 1.1588x over previous
//
#include <hip/hip_runtime.h>
#include <math.h>

#define B_   64
#define T_   128
#define NIN  256
#define H_   512
#define O_   256
#define M_   64
#define R_   512
#define EPS_ 1e-8f

typedef _Float16 h2 __attribute__((ext_vector_type(2)));

__device__ __forceinline__ float dot4(float4 a, float4 b) {
    return a.x*b.x + a.y*b.y + a.z*b.z + a.w*b.w;
}

// fp16 dot2 accumulate (v_dot2_f32_f16), bit-pattern operands
__device__ __forceinline__ float fd2(unsigned wu, unsigned hu, float acc) {
#if __has_builtin(__builtin_amdgcn_fdot2)
    return __builtin_amdgcn_fdot2(__builtin_bit_cast(h2, wu),
                                  __builtin_bit_cast(h2, hu), acc, false);
#else
    h2 w = __builtin_bit_cast(h2, wu), h = __builtin_bit_cast(h2, hu);
    return acc + (float)w[0]*(float)h[0] + (float)w[1]*(float)h[1];
#endif
}
#define FD4(W, HX, A) { A = fd2(W.x, HX.x, A); A = fd2(W.y, HX.y, A); \
                        A = fd2(W.z, HX.z, A); A = fd2(W.w, HX.w, A); }

__device__ __forceinline__ unsigned pk16(float a, float b) {
    return __builtin_bit_cast(unsigned, __builtin_amdgcn_cvt_pkrtz(a, b));
}
__device__ __forceinline__ unsigned short bits16(float v) {
    return __builtin_bit_cast(unsigned short, (_Float16)v);
}

template<int CTRL>
__device__ __forceinline__ float dpp_add(float v) {
    int t = __builtin_amdgcn_update_dpp(0, __float_as_int(v), CTRL, 0xF, 0xF, false);
    return v + __int_as_float(t);
}
__device__ __forceinline__ float red16(float v) {
    v = dpp_add<0xB1>(v);    // quad_perm xor1
    v = dpp_add<0x4E>(v);    // quad_perm xor2
    v = dpp_add<0x124>(v);   // row_ror:4
    v = dpp_add<0x128>(v);   // row_ror:8
    return v;
}
__device__ __forceinline__ float red64(float v) {
    v = red16(v);
    v += __shfl_xor(v, 16, 64);
    v += __shfl_xor(v, 32, 64);
    return v;
}
// partial reduction skipping xor1: lanes sub==0 / sub==1 keep separate sums
__device__ __forceinline__ float red64_pair(float v) {
    v = dpp_add<0x4E>(v);    // xor2
    v = dpp_add<0x124>(v);   // ror4
    v = dpp_add<0x128>(v);   // ror8
    v += __shfl_xor(v, 16, 64);
    v += __shfl_xor(v, 32, 64);
    return v;
}
__device__ __forceinline__ float tanh_f(float x)    { float e = __expf(2.f * x); return 1.f - 2.f / (e + 1.f); }
__device__ __forceinline__ float sigmoid_f(float x) { return 1.f / (1.f + __expf(-x)); }
__device__ __forceinline__ float softplus_f(float x){ return x > 20.f ? x : log1pf(__expf(x)); }

// ---------- Kernel 0: fp32 -> fp16 conversion of the 4 projection matrices ----------
__global__ __launch_bounds__(256) void w2h(
    const float* __restrict__ Wkr, const float* __restrict__ Wkw,
    const float* __restrict__ We,  const float* __restrict__ Wa,
    unsigned short* __restrict__ Wh)
{
    const int mi = blockIdx.x >> 5;          // 32 blocks per matrix
    const float* s = mi == 0 ? Wkr : mi == 1 ? Wkw : mi == 2 ? We : Wa;
    const int off = (blockIdx.x & 31) * 1024 + threadIdx.x * 4;
    float4 v = *(const float4*)&s[off];
    ushort4 o;
    o.x = bits16(v.x); o.y = bits16(v.y); o.z = bits16(v.z); o.w = bits16(v.w);
    *(ushort4*)&Wh[mi * 32768 + off] = o;
}

// ---------- Kernel 1: xin_h[bt][i] = fp16(x[bt] @ W_in.T + b_in) ----------
__global__ __launch_bounds__(256) void xin_gemm(
    const float* __restrict__ x, const float* __restrict__ Win,
    const float* __restrict__ bin, unsigned short* __restrict__ xin_h)
{
    __shared__ __align__(16) float xs[32 * NIN];
    const int tid  = threadIdx.x;
    const int row0 = blockIdx.x * 32;

    #pragma unroll
    for (int i = 0; i < 8; ++i) {
        int idx = i * 1024 + tid * 4;
        *(float4*)&xs[idx] = *(const float4*)&x[(size_t)row0 * NIN + idx];
    }
    __syncthreads();

    const int rg = tid >> 6;
    const int cg = tid & 63;
    const int c0 = cg * 8;
    float acc[8][8];
    #pragma unroll
    for (int r = 0; r < 8; ++r)
        #pragma unroll
        for (int c = 0; c < 8; ++c) acc[r][c] = 0.f;

    for (int k = 0; k < NIN; k += 4) {
        float4 xq[8];
        #pragma unroll
        for (int r = 0; r < 8; ++r) xq[r] = *(float4*)&xs[(rg * 8 + r) * NIN + k];
        #pragma unroll
        for (int c = 0; c < 8; ++c) {
            float4 w4 = *(const float4*)&Win[(size_t)(c0 + c) * NIN + k];
            #pragma unroll
            for (int r = 0; r < 8; ++r) acc[r][c] += dot4(xq[r], w4);
        }
    }
    #pragma unroll
    for (int r = 0; r < 8; ++r) {
        int grow = row0 + rg * 8 + r;
        ushort4 o0, o1;
        o0.x = bits16(acc[r][0] + bin[c0 + 0]);
        o0.y = bits16(acc[r][1] + bin[c0 + 1]);
        o0.z = bits16(acc[r][2] + bin[c0 + 2]);
        o0.w = bits16(acc[r][3] + bin[c0 + 3]);
        o1.x = bits16(acc[r][4] + bin[c0 + 4]);
        o1.y = bits16(acc[r][5] + bin[c0 + 5]);
        o1.z = bits16(acc[r][6] + bin[c0 + 6]);
        o1.w = bits16(acc[r][7] + bin[c0 + 7]);
        *(ushort4*)&xin_h[(size_t)grow * H_ + c0]     = o0;
        *(ushort4*)&xin_h[(size_t)grow * H_ + c0 + 4] = o1;
    }
}

// ---------- Kernel 2: recurrent loop, one WG per batch element ----------
__global__ __launch_bounds__(1024, 4) void ntm_loop(
    const unsigned short* __restrict__ xin_h,
    const float* __restrict__ h0,
    const float* __restrict__ frf0, const float* __restrict__ fwf0,
    const float* __restrict__ m0,
    const unsigned short* __restrict__ Wh,      // fp16 [Wkr;Wkw;We;Wa]
    const float* __restrict__ bkr_g, const float* __restrict__ bkw_g,
    const float* __restrict__ be_g,  const float* __restrict__ ba_g,
    const float* __restrict__ Wbr, const float* __restrict__ bbr_g,
    const float* __restrict__ Wgr, const float* __restrict__ bgr_g,
    const float* __restrict__ Wbw, const float* __restrict__ bbw_g,
    const float* __restrict__ Wgw, const float* __restrict__ bgw_g,
    const float* __restrict__ Wread, const float* __restrict__ bread_g,
    float* __restrict__ h_all)
{
    __shared__ __align__(16) unsigned short hh[H_];   // fp16 h (1 KB)
    __shared__ __align__(16) float hbuf[H_];          // fp32 h (2 KB)
    __shared__ __align__(16) unsigned wrh[R_ * 36];   // fp16 Wread, stride-36 pad (72 KB)
    __shared__ float frf2[2][R_];
    __shared__ float fwf2[2][R_];
    __shared__ float dotsR[R_];
    __shared__ float dotsW[R_];
    __shared__ __align__(16) float proj4[4 * M_];     // kR | kW | eV | aV
    __shared__ __align__(16) float rt[M_];
    __shared__ __align__(16) float Whead[4 * H_];     // 8 KB: Wbr,Wgr,Wbw,Wgw
    __shared__ float wsumR[16], wsumW[16];
    __shared__ float bias4[4 * M_];
    __shared__ float bhead[4];
    __shared__ float scal[4];   // 0:beta_r 1:g_r 2:beta_w 3:g_w

    const int b    = blockIdx.x;
    const int tid  = threadIdx.x;
    const int wave = tid >> 6, lane = tid & 63;
    const int g    = lane >> 4, sub = lane & 15;
    const int nidx = wave * 32 + (lane & 31);   // phase-D neuron
    const int dhalf = lane >> 5;
    const int row = tid >> 4, s16 = tid & 15;   // phase-A mapping

    // ---- init ----
    const float* mg = m0 + (size_t)b * (R_ * M_);
    float4 mreg[8];                             // register-resident memory rows
    #pragma unroll
    for (int i = 0; i < 8; ++i)
        mreg[i] = *(const float4*)&mg[(wave * 32 + i * 4 + g) * M_ + sub * 4];

    // register/AGPR-resident projection weights: 4 matrices x 32 fp16
    uint4 w16[16];   // [m*4+j]
    #pragma unroll
    for (int m = 0; m < 4; ++m)
        #pragma unroll
        for (int j = 0; j < 4; ++j)
            w16[m * 4 + j] = *(const uint4*)&Wh[m * 32768 + row * H_ + s16 * 32 + j * 8];

    if (tid < H_) { float hv = h0[b * H_ + tid]; hbuf[tid] = hv; hh[tid] = bits16(hv); }
    if (tid < R_) { frf2[0][tid] = frf0[b * R_ + tid]; fwf2[0][tid] = fwf0[b * R_ + tid]; }
    if (tid < M_) {
        bias4[tid]          = bkr_g[tid];
        bias4[M_ + tid]     = bkw_g[tid];
        bias4[2 * M_ + tid] = be_g[tid];
        bias4[3 * M_ + tid] = ba_g[tid];
    }
    #pragma unroll
    for (int k2 = 0; k2 < 2; ++k2) {
        int idx = k2 * 1024 + tid;
        int mi = idx >> 9;
        const float* src = mi == 0 ? Wbr : mi == 1 ? Wgr : mi == 2 ? Wbw : Wgw;
        Whead[idx] = src[idx & (H_ - 1)];
    }
    if (tid < 4) bhead[tid] = (tid == 0 ? bbr_g : tid == 1 ? bgr_g : tid == 2 ? bbw_g : bgw_g)[0];

    // Wread -> LDS fp16, stride-36 rows (bank-uniform b128 reads)
    {
        const int wn = tid >> 1, wd = tid & 1;      // neuron, half
        const float* wrp = Wread + (size_t)wn * M_ + wd * 32;
        #pragma unroll
        for (int c = 0; c < 4; ++c) {
            float4 wa = *(const float4*)&wrp[c * 8];
            float4 wb = *(const float4*)&wrp[c * 8 + 4];
            uint4 o;
            o.x = pk16(wa.x, wa.y); o.y = pk16(wa.z, wa.w);
            o.z = pk16(wb.x, wb.y); o.w = pk16(wb.z, wb.w);
            *(uint4*)&wrh[wn * 36 + wd * 16 + c * 4] = o;
        }
    }
    const float breg = (dhalf == 0) ? bread_g[nidx] : 0.f;

    // initial row norms -> registers (valid in all 16 sub-lanes)
    float nreg[8];
    #pragma unroll
    for (int i = 0; i < 8; ++i) {
        float4 v = mreg[i];
        nreg[i] = red16(v.x*v.x + v.y*v.y + v.z*v.z + v.w*v.w);
    }
    __syncthreads();

    for (int t = 0; t < T_; ++t) {
        const int cur = t & 1, nxt = cur ^ 1;

        // ---- Phase A: projections (fp16 dot2) + scalar heads + prefetch ----
        unsigned short xbits = 0;
        if (dhalf == 0) xbits = xin_h[(size_t)(b * T_ + t) * H_ + nidx];
        if (wave == 15) rt[lane] = 0.f;
        {
            float a0 = 0, a1 = 0, a2 = 0, a3 = 0;
            #pragma unroll
            for (int j = 0; j < 4; ++j) {
                uint4 hx = *(const uint4*)&hh[s16 * 32 + j * 8];
                FD4(w16[0 * 4 + j], hx, a0);
                FD4(w16[1 * 4 + j], hx, a1);
                FD4(w16[2 * 4 + j], hx, a2);
                FD4(w16[3 * 4 + j], hx, a3);
            }
            a0 = red16(a0); a1 = red16(a1); a2 = red16(a2); a3 = red16(a3);
            // merged activation: one exp + one rcp for all four heads
            float av = (s16 == 0) ? a0 : (s16 == 1) ? a1 : (s16 == 2) ? a2 : a3;
            float xv = av + bias4[(s16 & 3) * M_ + row];
            float e  = __expf((s16 == 2) ? -xv : 2.f * xv);
            float rcp = 1.f / (1.f + e);
            float act = (s16 == 2) ? rcp : 1.f - 2.f * rcp;   // sigmoid : tanh
            if (s16 < 4) proj4[s16 * M_ + row] = act;

            if (tid < 256) {   // 4 scalar heads from LDS weights
                const int sc = tid >> 6;
                const float* Wp = &Whead[sc * H_ + lane * 8];
                float acc = dot4(*(float4*)&hbuf[lane * 8],     *(const float4*)&Wp[0])
                          + dot4(*(float4*)&hbuf[lane * 8 + 4], *(const float4*)&Wp[4]);
                acc = red64(acc);
                if (lane == 0) {
                    float hv = acc + bhead[sc];
                    scal[sc] = (sc & 1) ? sigmoid_f(hv) : softplus_f(hv);
                }
            }
        }
        __syncthreads();   // B1

        // ---- Phase B: content dots -> exp scores + fused partial sums ----
        {
            float4 kr4 = *(float4*)&proj4[sub * 4];
            float4 kw4 = *(float4*)&proj4[M_ + sub * 4];
            float snKR = sqrtf(red16(dot4(kr4, kr4)));
            float snKW = sqrtf(red16(dot4(kw4, kw4)));
            float beta_r = scal[0], beta_w = scal[2];
            const bool isW = (sub == 1);
            float snK = isW ? snKW : snKR;
            float bta = isW ? beta_w : beta_r;
            float eacc = 0.f;
            #pragma unroll
            for (int i = 0; i < 8; ++i) {
                int r = wave * 32 + i * 4 + g;
                float4 v = mreg[i];
                float dr = red16(dot4(kr4, v));
                float dw = red16(dot4(kw4, v));
                if (sub < 2) {
                    float d  = isW ? dw : dr;
                    float sn = sqrtf(nreg[i]);
                    float e  = __expf(bta * d / (snK * sn + EPS_));
                    *(isW ? &dotsW[r] : &dotsR[r]) = e;
                    eacc += e;
                }
            }
            float vsum = red64_pair(eacc);   // sub==0 -> eR sum, sub==1 -> eW sum
            if      (lane == 0) wsumR[wave] = vsum;
            else if (lane == 1) wsumW[wave] = vsum;
        }
        __syncthreads();   // B2

        // ---- Phase C: filters (shfl broadcast) + mem update + r_t + norms ----
        {
            float totR = red16(wsumR[lane & 15]);
            float totW = red16(wsumW[lane & 15]);
            float fw_r = 0.f, fw_w = 0.f;
            if (lane < 32) {
                const int r = wave * 32 + lane;
                float invR = 1.f / totR, invW = 1.f / totW;
                const int rm = (r + R_ - 1) & (R_ - 1), rp = (r + 1) & (R_ - 1);
                float gr = scal[1], gw = scal[3];

                float f0 = gr * dotsR[r]  * invR + (1.f - gr) * frf2[cur][r];
                float fm = gr * dotsR[rm] * invR + (1.f - gr) * frf2[cur][rm];
                float fp = gr * dotsR[rp] * invR + (1.f - gr) * frf2[cur][rp];
                frf2[nxt][r] = f0;
                fw_r = 0.5f * f0 + 0.5f * (0.25f * fm + 0.5f * f0 + 0.25f * fp);

                float q0 = gw * dotsW[r]  * invW + (1.f - gw) * fwf2[cur][r];
                float qm = gw * dotsW[rm] * invW + (1.f - gw) * fwf2[cur][rm];
                float qp = gw * dotsW[rp] * invW + (1.f - gw) * fwf2[cur][rp];
                fwf2[nxt][r] = q0;
                fw_w = 0.5f * q0 + 0.5f * (0.25f * qm + 0.5f * q0 + 0.25f * qp);
            }

            float4 e4 = *(float4*)&proj4[2 * M_ + sub * 4];
            float4 a4 = *(float4*)&proj4[3 * M_ + sub * 4];
            float rt0 = 0, rt1 = 0, rt2 = 0, rt3 = 0;
            #pragma unroll
            for (int i = 0; i < 8; ++i) {
                float wr = __shfl(fw_r, i * 4 + g, 64);
                float ww = __shfl(fw_w, i * 4 + g, 64);
                float4 v = mreg[i];
                rt0 += wr * v.x; rt1 += wr * v.y; rt2 += wr * v.z; rt3 += wr * v.w;
                float4 nv;
                nv.x = v.x * (1.f - ww * e4.x) + ww * a4.x;
                nv.y = v.y * (1.f - ww * e4.y) + ww * a4.y;
                nv.z = v.z * (1.f - ww * e4.z) + ww * a4.z;
                nv.w = v.w * (1.f - ww * e4.w) + ww * a4.w;
                mreg[i] = nv;
                nreg[i] = red16(nv.x*nv.x + nv.y*nv.y + nv.z*nv.z + nv.w*nv.w);
            }
            rt0 += __shfl_xor(rt0, 16, 64); rt0 += __shfl_xor(rt0, 32, 64);
            rt1 += __shfl_xor(rt1, 16, 64); rt1 += __shfl_xor(rt1, 32, 64);
            rt2 += __shfl_xor(rt2, 16, 64); rt2 += __shfl_xor(rt2, 32, 64);
            rt3 += __shfl_xor(rt3, 16, 64); rt3 += __shfl_xor(rt3, 32, 64);
            if (g == 0) {
                atomicAdd(&rt[sub * 4 + 0], rt0);
                atomicAdd(&rt[sub * 4 + 1], rt1);
                atomicAdd(&rt[sub * 4 + 2], rt2);
                atomicAdd(&rt[sub * 4 + 3], rt3);
            }
        }
        __syncthreads();   // B3

        // ---- Phase D: h = relu(xin + Wread @ r_t + b); stride-36 LDS rows ----
        {
            const int base = nidx * 36 + dhalf * 16;
            float acc = 0.f;
            #pragma unroll
            for (int c = 0; c < 4; ++c) {
                uint4 wq = *(uint4*)&wrh[base + c * 4];
                float4 ra = *(float4*)&rt[dhalf * 32 + c * 8];
                float4 rb = *(float4*)&rt[dhalf * 32 + c * 8 + 4];
                unsigned p0 = pk16(ra.x, ra.y), p1 = pk16(ra.z, ra.w);
                unsigned p2 = pk16(rb.x, rb.y), p3 = pk16(rb.z, rb.w);
                acc = fd2(wq.x, p0, acc); acc = fd2(wq.y, p1, acc);
                acc = fd2(wq.z, p2, acc); acc = fd2(wq.w, p3, acc);
            }
            acc += __shfl_xor(acc, 32, 64);
            if (dhalf == 0) {
                float xv = (float)__builtin_bit_cast(_Float16, xbits);
                float hv = fmaxf(xv + acc + breg, 0.f);
                hbuf[nidx] = hv;
                hh[nidx] = bits16(hv);
                h_all[(size_t)(b * T_ + t) * H_ + nidx] = hv;
            }
        }
        __syncthreads();   // B4
    }
}

// ---------- Kernel 3: out = sigmoid(h_all @ W_out.T + b_out) ----------
__global__ __launch_bounds__(256) void out_gemm(
    const float* __restrict__ h_all, const float* __restrict__ Wout,
    const float* __restrict__ bout, float* __restrict__ out)
{
    __shared__ __align__(16) float hs[32 * H_];
    const int tid  = threadIdx.x;
    const int row0 = blockIdx.x * 32;

    #pragma unroll
    for (int i = 0; i < 16; ++i) {
        int idx = i * 1024 + tid * 4;
        *(float4*)&hs[idx] = *(const float4*)&h_all[(size_t)row0 * H_ + idx];
    }
    __syncthreads();

    const int rg = tid >> 6;
    const int cg = tid & 63;
    const int c0 = cg * 4;
    float acc[8][4];
    #pragma unroll
    for (int r = 0; r < 8; ++r)
        #pragma unroll
        for (int c = 0; c < 4; ++c) acc[r][c] = 0.f;

    for (int k = 0; k < H_; k += 4) {
        float4 xq[8];
        #pragma unroll
        for (int r = 0; r < 8; ++r) xq[r] = *(float4*)&hs[(rg * 8 + r) * H_ + k];
        #pragma unroll
        for (int c = 0; c < 4; ++c) {
            float4 w4 = *(const float4*)&Wout[(size_t)(c0 + c) * H_ + k];
            #pragma unroll
            for (int r = 0; r < 8; ++r) acc[r][c] += dot4(xq[r], w4);
        }
    }
    #pragma unroll
    for (int r = 0; r < 8; ++r) {
        int grow = row0 + rg * 8 + r;
        float4 o4;
        o4.x = sigmoid_f(acc[r][0] + bout[c0 + 0]);
        o4.y = sigmoid_f(acc[r][1] + bout[c0 + 1]);
        o4.z = sigmoid_f(acc[r][2] + bout[c0 + 2]);
        o4.w = sigmoid_f(acc[r][3] + bout[c0 + 3]);
        *(float4*)&out[(size_t)grow * O_ + c0] = o4;
    }
}

extern "C" void kernel_launch(void* const* d_in, const int* in_sizes, int n_in,
                              void* d_out, int out_size, void* d_ws, size_t ws_size,
                              hipStream_t stream) {
    const float* x     = (const float*)d_in[0];
    const float* h0    = (const float*)d_in[1];
    const float* frf   = (const float*)d_in[2];
    const float* fwf   = (const float*)d_in[4];
    const float* m0    = (const float*)d_in[6];
    const float* Win   = (const float*)d_in[7];
    const float* bin   = (const float*)d_in[8];
    const float* Wread = (const float*)d_in[9];
    const float* bread = (const float*)d_in[10];
    const float* Wout  = (const float*)d_in[11];
    const float* bout  = (const float*)d_in[12];
    const float* Wkr   = (const float*)d_in[13];
    const float* bkr   = (const float*)d_in[14];
    const float* Wbr   = (const float*)d_in[15];
    const float* bbr   = (const float*)d_in[16];
    const float* Wgr   = (const float*)d_in[17];
    const float* bgr   = (const float*)d_in[18];
    const float* Wkw   = (const float*)d_in[19];
    const float* bkw   = (const float*)d_in[20];
    const float* Wbw   = (const float*)d_in[21];
    const float* bbw   = (const float*)d_in[22];
    const float* Wgw   = (const float*)d_in[23];
    const float* bgw   = (const float*)d_in[24];
    const float* We    = (const float*)d_in[25];
    const float* be    = (const float*)d_in[26];
    const float* Wa    = (const float*)d_in[27];
    const float* ba    = (const float*)d_in[28];

    unsigned short* xin_h = (unsigned short*)d_ws;                              // 8 MB
    float* h_all = (float*)((char*)d_ws + (size_t)B_ * T_ * H_ * 2);            // 16 MB
    unsigned short* Wh = (unsigned short*)((char*)d_ws + (size_t)B_ * T_ * H_ * 6);  // 256 KB

    w2h<<<128, 256, 0, stream>>>(Wkr, Wkw, We, Wa, Wh);
    xin_gemm<<<256, 256, 0, stream>>>(x, Win, bin, xin_h);
    ntm_loop<<<B_, 1024, 0, stream>>>(xin_h, h0, frf, fwf, m0,
        Wh, bkr, bkw, be, ba,
        Wbr, bbr, Wgr, bgr, Wbw, bbw, Wgw, bgw,
        Wread, bread, h_all);
    out_gemm<<<256, 256, 0, stream>>>(h_all, Wout, bout, (float*)d_out);
}

// Round 7
// 1781.097 us; speedup vs baseline: 5.4596x; 1.0670x over previous
//
#include <hip/hip_runtime.h>
#include <math.h>

#define B_   64
#define T_   128
#define NIN  256
#define H_   512
#define O_   256
#define M_   64
#define R_   512
#define EPS_ 1e-8f

typedef _Float16 h2 __attribute__((ext_vector_type(2)));

__device__ __forceinline__ float dot4(float4 a, float4 b) {
    return a.x*b.x + a.y*b.y + a.z*b.z + a.w*b.w;
}

// fp16 dot2 accumulate (v_dot2_f32_f16), bit-pattern operands
__device__ __forceinline__ float fd2(unsigned wu, unsigned hu, float acc) {
#if __has_builtin(__builtin_amdgcn_fdot2)
    return __builtin_amdgcn_fdot2(__builtin_bit_cast(h2, wu),
                                  __builtin_bit_cast(h2, hu), acc, false);
#else
    h2 w = __builtin_bit_cast(h2, wu), h = __builtin_bit_cast(h2, hu);
    return acc + (float)w[0]*(float)h[0] + (float)w[1]*(float)h[1];
#endif
}
#define FD4(W, HX, A) { A = fd2(W.x, HX.x, A); A = fd2(W.y, HX.y, A); \
                        A = fd2(W.z, HX.z, A); A = fd2(W.w, HX.w, A); }

__device__ __forceinline__ unsigned pk16(float a, float b) {
    return __builtin_bit_cast(unsigned, __builtin_amdgcn_cvt_pkrtz(a, b));
}
__device__ __forceinline__ unsigned short bits16(float v) {
    return __builtin_bit_cast(unsigned short, (_Float16)v);
}

template<int CTRL>
__device__ __forceinline__ float dpp_add(float v) {
    int t = __builtin_amdgcn_update_dpp(0, __float_as_int(v), CTRL, 0xF, 0xF, false);
    return v + __int_as_float(t);
}
template<int CTRL>
__device__ __forceinline__ float dpp_mov(float v) {
    return __int_as_float(__builtin_amdgcn_update_dpp(0, __float_as_int(v), CTRL, 0xF, 0xF, false));
}
__device__ __forceinline__ float red16(float v) {
    v = dpp_add<0xB1>(v);    // quad_perm xor1
    v = dpp_add<0x4E>(v);    // quad_perm xor2
    v = dpp_add<0x124>(v);   // row_ror:4
    v = dpp_add<0x128>(v);   // row_ror:8
    return v;
}
__device__ __forceinline__ float red64(float v) {
    v = red16(v);
    v += __shfl_xor(v, 16, 64);
    v += __shfl_xor(v, 32, 64);
    return v;
}
// partial reduction skipping xor1: lanes sub==0 / sub==1 keep separate sums
__device__ __forceinline__ float red64_pair(float v) {
    v = dpp_add<0x4E>(v);    // xor2
    v = dpp_add<0x124>(v);   // ror4
    v = dpp_add<0x128>(v);   // ror8
    v += __shfl_xor(v, 16, 64);
    v += __shfl_xor(v, 32, 64);
    return v;
}
__device__ __forceinline__ float sigmoid_f(float x) { return 1.f / (1.f + __expf(-x)); }
__device__ __forceinline__ float softplus_f(float x){ return x > 20.f ? x : log1pf(__expf(x)); }

// ---------- Kernel 0: fp32 -> fp16 conversion of the 4 projection matrices ----------
__global__ __launch_bounds__(256) void w2h(
    const float* __restrict__ Wkr, const float* __restrict__ Wkw,
    const float* __restrict__ We,  const float* __restrict__ Wa,
    unsigned short* __restrict__ Wh)
{
    const int mi = blockIdx.x >> 5;          // 32 blocks per matrix
    const float* s = mi == 0 ? Wkr : mi == 1 ? Wkw : mi == 2 ? We : Wa;
    const int off = (blockIdx.x & 31) * 1024 + threadIdx.x * 4;
    float4 v = *(const float4*)&s[off];
    ushort4 o;
    o.x = bits16(v.x); o.y = bits16(v.y); o.z = bits16(v.z); o.w = bits16(v.w);
    *(ushort4*)&Wh[mi * 32768 + off] = o;
}

// ---------- Kernel 1: xin_h[bt][i] = fp16(x[bt] @ W_in.T + b_in) ----------
__global__ __launch_bounds__(256) void xin_gemm(
    const float* __restrict__ x, const float* __restrict__ Win,
    const float* __restrict__ bin, unsigned short* __restrict__ xin_h)
{
    __shared__ __align__(16) float xs[32 * NIN];
    const int tid  = threadIdx.x;
    const int row0 = blockIdx.x * 32;

    #pragma unroll
    for (int i = 0; i < 8; ++i) {
        int idx = i * 1024 + tid * 4;
        *(float4*)&xs[idx] = *(const float4*)&x[(size_t)row0 * NIN + idx];
    }
    __syncthreads();

    const int rg = tid >> 6;
    const int cg = tid & 63;
    const int c0 = cg * 8;
    float acc[8][8];
    #pragma unroll
    for (int r = 0; r < 8; ++r)
        #pragma unroll
        for (int c = 0; c < 8; ++c) acc[r][c] = 0.f;

    for (int k = 0; k < NIN; k += 4) {
        float4 xq[8];
        #pragma unroll
        for (int r = 0; r < 8; ++r) xq[r] = *(float4*)&xs[(rg * 8 + r) * NIN + k];
        #pragma unroll
        for (int c = 0; c < 8; ++c) {
            float4 w4 = *(const float4*)&Win[(size_t)(c0 + c) * NIN + k];
            #pragma unroll
            for (int r = 0; r < 8; ++r) acc[r][c] += dot4(xq[r], w4);
        }
    }
    #pragma unroll
    for (int r = 0; r < 8; ++r) {
        int grow = row0 + rg * 8 + r;
        ushort4 o0, o1;
        o0.x = bits16(acc[r][0] + bin[c0 + 0]);
        o0.y = bits16(acc[r][1] + bin[c0 + 1]);
        o0.z = bits16(acc[r][2] + bin[c0 + 2]);
        o0.w = bits16(acc[r][3] + bin[c0 + 3]);
        o1.x = bits16(acc[r][4] + bin[c0 + 4]);
        o1.y = bits16(acc[r][5] + bin[c0 + 5]);
        o1.z = bits16(acc[r][6] + bin[c0 + 6]);
        o1.w = bits16(acc[r][7] + bin[c0 + 7]);
        *(ushort4*)&xin_h[(size_t)grow * H_ + c0]     = o0;
        *(ushort4*)&xin_h[(size_t)grow * H_ + c0 + 4] = o1;
    }
}

// ---------- Kernel 2: recurrent loop, one WG per batch element ----------
__global__ __launch_bounds__(1024, 4) void ntm_loop(
    const unsigned short* __restrict__ xin_h,
    const float* __restrict__ h0,
    const float* __restrict__ frf0, const float* __restrict__ fwf0,
    const float* __restrict__ m0,
    const unsigned short* __restrict__ Wh,      // fp16 [Wkr;Wkw;We;Wa]
    const float* __restrict__ bkr_g, const float* __restrict__ bkw_g,
    const float* __restrict__ be_g,  const float* __restrict__ ba_g,
    const float* __restrict__ Wbr, const float* __restrict__ bbr_g,
    const float* __restrict__ Wgr, const float* __restrict__ bgr_g,
    const float* __restrict__ Wbw, const float* __restrict__ bbw_g,
    const float* __restrict__ Wgw, const float* __restrict__ bgw_g,
    const float* __restrict__ Wread, const float* __restrict__ bread_g,
    float* __restrict__ h_all)
{
    __shared__ __align__(16) unsigned short hh40[16 * 40];  // fp16 h, stride-40 rows
    __shared__ __align__(16) float hbuf[H_];                // fp32 h
    __shared__ __align__(16) unsigned wrh[R_ * 36];         // fp16 Wread, stride-36 (72 KB)
    __shared__ float frf2[2][R_];
    __shared__ float fwf2[2][R_];
    __shared__ float dotsR[R_];
    __shared__ float dotsW[R_];
    __shared__ float wread_s[R_];
    __shared__ float wwrite_s[R_];
    __shared__ __align__(16) float proj4[4 * M_];     // kR | kW | eV | aV
    __shared__ __align__(16) float rt[M_];
    __shared__ __align__(16) float Whead[4 * H_];     // 8 KB: Wbr,Wgr,Wbw,Wgw
    __shared__ float wsumR[16], wsumW[16];
    __shared__ float bias4[4 * M_];
    __shared__ float bhead[4];
    __shared__ float scal[4];   // 0:beta_r 1:g_r 2:beta_w 3:g_w

    const int b    = blockIdx.x;
    const int tid  = threadIdx.x;
    const int wave = tid >> 6, lane = tid & 63;
    const int g    = lane >> 4, sub = lane & 15;
    const int nidx = wave * 32 + (lane & 31);   // phase-D neuron
    const int dhalf = lane >> 5;
    const int row = tid >> 4, s16 = tid & 15;   // phase-A mapping

    // ---- init ----
    const float* mg = m0 + (size_t)b * (R_ * M_);
    float4 mreg[8];                             // register-resident memory rows
    #pragma unroll
    for (int i = 0; i < 8; ++i)
        mreg[i] = *(const float4*)&mg[(wave * 32 + i * 4 + g) * M_ + sub * 4];

    // register/AGPR-resident projection weights: 4 matrices x 32 fp16
    uint4 w16[16];   // [m*4+j]
    #pragma unroll
    for (int m = 0; m < 4; ++m)
        #pragma unroll
        for (int j = 0; j < 4; ++j)
            w16[m * 4 + j] = *(const uint4*)&Wh[m * 32768 + row * H_ + s16 * 32 + j * 8];

    if (tid < H_) {
        float hv = h0[b * H_ + tid];
        hbuf[tid] = hv;
        hh40[(tid >> 5) * 40 + (tid & 31)] = bits16(hv);
    }
    if (tid < R_) { frf2[0][tid] = frf0[b * R_ + tid]; fwf2[0][tid] = fwf0[b * R_ + tid]; }
    if (tid < M_) {
        bias4[tid]          = bkr_g[tid];
        bias4[M_ + tid]     = bkw_g[tid];
        bias4[2 * M_ + tid] = be_g[tid];
        bias4[3 * M_ + tid] = ba_g[tid];
    }
    #pragma unroll
    for (int k2 = 0; k2 < 2; ++k2) {
        int idx = k2 * 1024 + tid;
        int mi = idx >> 9;
        const float* src = mi == 0 ? Wbr : mi == 1 ? Wgr : mi == 2 ? Wbw : Wgw;
        Whead[idx] = src[idx & (H_ - 1)];
    }
    if (tid < 4) bhead[tid] = (tid == 0 ? bbr_g : tid == 1 ? bgr_g : tid == 2 ? bbw_g : bgw_g)[0];

    // Wread -> LDS fp16, stride-36 rows (bank-uniform b128 reads)
    {
        const int wn = tid >> 1, wd = tid & 1;      // neuron, half
        const float* wrp = Wread + (size_t)wn * M_ + wd * 32;
        #pragma unroll
        for (int c = 0; c < 4; ++c) {
            float4 wa = *(const float4*)&wrp[c * 8];
            float4 wb = *(const float4*)&wrp[c * 8 + 4];
            uint4 o;
            o.x = pk16(wa.x, wa.y); o.y = pk16(wa.z, wa.w);
            o.z = pk16(wb.x, wb.y); o.w = pk16(wb.z, wb.w);
            *(uint4*)&wrh[wn * 36 + wd * 16 + c * 4] = o;
        }
    }
    const float breg = (dhalf == 0) ? bread_g[nidx] : 0.f;
    __syncthreads();

    for (int t = 0; t < T_; ++t) {
        const int cur = t & 1, nxt = cur ^ 1;

        // ---- Phase A: projections (fp16 dot2) + scalar heads + prefetch ----
        unsigned short xbits = 0;
        if (dhalf == 0) xbits = xin_h[(size_t)(b * T_ + t) * H_ + nidx];
        if (wave == 15) rt[lane] = 0.f;
        {
            float a0 = 0, a1 = 0, a2 = 0, a3 = 0;
            #pragma unroll
            for (int j = 0; j < 4; ++j) {
                uint4 hx = *(const uint4*)&hh40[s16 * 40 + j * 8];
                FD4(w16[0 * 4 + j], hx, a0);
                FD4(w16[1 * 4 + j], hx, a1);
                FD4(w16[2 * 4 + j], hx, a2);
                FD4(w16[3 * 4 + j], hx, a3);
            }
            a0 = red16(a0); a1 = red16(a1); a2 = red16(a2); a3 = red16(a3);
            // merged activation: one exp + one rcp for all four heads
            float av = (s16 == 0) ? a0 : (s16 == 1) ? a1 : (s16 == 2) ? a2 : a3;
            float xv = av + bias4[(s16 & 3) * M_ + row];
            float e  = __expf((s16 == 2) ? -xv : 2.f * xv);
            float rcp = 1.f / (1.f + e);
            float act = (s16 == 2) ? rcp : 1.f - 2.f * rcp;   // sigmoid : tanh
            if (s16 < 4) proj4[s16 * M_ + row] = act;

            if (tid < 256) {   // 4 scalar heads, interleaved (conflict-free) reads
                const int sc = tid >> 6;
                float acc = 0.f;
                #pragma unroll
                for (int j = 0; j < 8; ++j)
                    acc += hbuf[j * 64 + lane] * Whead[sc * H_ + j * 64 + lane];
                acc = red64(acc);
                if (lane == 0) {
                    float hv = acc + bhead[sc];
                    scal[sc] = (sc & 1) ? sigmoid_f(hv) : softplus_f(hv);
                }
            }
        }
        __syncthreads();   // B1

        // ---- Phase B: fused {dot_r, dot_w, norm} row reductions -> exp scores ----
        {
            float4 kr4 = *(float4*)&proj4[sub * 4];
            float4 kw4 = *(float4*)&proj4[M_ + sub * 4];
            float snKR = sqrtf(red16(dot4(kr4, kr4)));
            float snKW = sqrtf(red16(dot4(kw4, kw4)));
            const bool isW = (sub == 1);
            float bta = isW ? scal[2] : scal[0];
            float snK = isW ? snKW : snKR;
            float eacc = 0.f;
            #pragma unroll
            for (int i = 0; i < 8; ++i) {
                int r = wave * 32 + i * 4 + g;
                float4 v = mreg[i];
                float c = dot4(kr4, v);
                float d = dot4(kw4, v);
                float n = dot4(v, v);
                float c2 = dpp_add<0xB1>(c), d2 = dpp_add<0xB1>(d), n2 = dpp_add<0xB1>(n);
                float c4 = dpp_add<0x4E>(c2), d4 = dpp_add<0x4E>(d2), n4 = dpp_add<0x4E>(n2);
                const int q = sub & 3;
                float z = (q == 0) ? c4 : (q == 1 ? d4 : n4);
                z = dpp_add<0x124>(z);      // sum over quads (position-preserving)
                z = dpp_add<0x128>(z);
                float nt = dpp_mov<0xAA>(z); // broadcast quad-lane 2 (norm total)
                if (sub < 2) {
                    float sn = sqrtf(nt);
                    float ee = __expf(bta * z / (snK * sn + EPS_));
                    *(isW ? &dotsW[r] : &dotsR[r]) = ee;
                    eacc += ee;
                }
            }
            float vsum = red64_pair(eacc);   // sub==0 -> eR sum, sub==1 -> eW sum
            if      (lane == 0) wsumR[wave] = vsum;
            else if (lane == 1) wsumW[wave] = vsum;
        }
        __syncthreads();   // B2

        // ---- Phase C: filters (LDS broadcast) + mem update + r_t partials ----
        {
            float totR = red16(wsumR[lane & 15]);
            float totW = red16(wsumW[lane & 15]);
            if (lane < 32) {
                const int r = wave * 32 + lane;
                float invR = 1.f / totR, invW = 1.f / totW;
                const int rm = (r + R_ - 1) & (R_ - 1), rp = (r + 1) & (R_ - 1);
                float gr = scal[1], gw = scal[3];

                float f0 = gr * dotsR[r]  * invR + (1.f - gr) * frf2[cur][r];
                float fm = gr * dotsR[rm] * invR + (1.f - gr) * frf2[cur][rm];
                float fp = gr * dotsR[rp] * invR + (1.f - gr) * frf2[cur][rp];
                frf2[nxt][r] = f0;
                wread_s[r] = 0.5f * f0 + 0.5f * (0.25f * fm + 0.5f * f0 + 0.25f * fp);

                float q0 = gw * dotsW[r]  * invW + (1.f - gw) * fwf2[cur][r];
                float qm = gw * dotsW[rm] * invW + (1.f - gw) * fwf2[cur][rm];
                float qp = gw * dotsW[rp] * invW + (1.f - gw) * fwf2[cur][rp];
                fwf2[nxt][r] = q0;
                wwrite_s[r] = 0.5f * q0 + 0.5f * (0.25f * qm + 0.5f * q0 + 0.25f * qp);
            }
            __builtin_amdgcn_wave_barrier();   // same-wave LDS write->read ordering

            float4 e4 = *(float4*)&proj4[2 * M_ + sub * 4];
            float4 a4 = *(float4*)&proj4[3 * M_ + sub * 4];
            float rt0 = 0, rt1 = 0, rt2 = 0, rt3 = 0;
            #pragma unroll
            for (int i = 0; i < 8; ++i) {
                int r = wave * 32 + i * 4 + g;
                float wr = wread_s[r], ww = wwrite_s[r];   // broadcast reads
                float4 v = mreg[i];
                rt0 += wr * v.x; rt1 += wr * v.y; rt2 += wr * v.z; rt3 += wr * v.w;
                float4 nv;
                nv.x = v.x * (1.f - ww * e4.x) + ww * a4.x;
                nv.y = v.y * (1.f - ww * e4.y) + ww * a4.y;
                nv.z = v.z * (1.f - ww * e4.z) + ww * a4.z;
                nv.w = v.w * (1.f - ww * e4.w) + ww * a4.w;
                mreg[i] = nv;
            }
            rt0 += __shfl_xor(rt0, 16, 64); rt0 += __shfl_xor(rt0, 32, 64);
            rt1 += __shfl_xor(rt1, 16, 64); rt1 += __shfl_xor(rt1, 32, 64);
            rt2 += __shfl_xor(rt2, 16, 64); rt2 += __shfl_xor(rt2, 32, 64);
            rt3 += __shfl_xor(rt3, 16, 64); rt3 += __shfl_xor(rt3, 32, 64);
            if (g == 0) {
                atomicAdd(&rt[sub * 4 + 0], rt0);
                atomicAdd(&rt[sub * 4 + 1], rt1);
                atomicAdd(&rt[sub * 4 + 2], rt2);
                atomicAdd(&rt[sub * 4 + 3], rt3);
            }
        }
        __syncthreads();   // B3

        // ---- Phase D: h = relu(xin + Wread @ r_t + b); stride-36 LDS rows ----
        {
            const int base = nidx * 36 + dhalf * 16;
            float acc = 0.f;
            #pragma unroll
            for (int c = 0; c < 4; ++c) {
                uint4 wq = *(uint4*)&wrh[base + c * 4];
                float4 ra = *(float4*)&rt[dhalf * 32 + c * 8];
                float4 rb = *(float4*)&rt[dhalf * 32 + c * 8 + 4];
                unsigned p0 = pk16(ra.x, ra.y), p1 = pk16(ra.z, ra.w);
                unsigned p2 = pk16(rb.x, rb.y), p3 = pk16(rb.z, rb.w);
                acc = fd2(wq.x, p0, acc); acc = fd2(wq.y, p1, acc);
                acc = fd2(wq.z, p2, acc); acc = fd2(wq.w, p3, acc);
            }
            acc += __shfl_xor(acc, 32, 64);
            if (dhalf == 0) {
                float xv = (float)__builtin_bit_cast(_Float16, xbits);
                float hv = fmaxf(xv + acc + breg, 0.f);
                hbuf[nidx] = hv;
                hh40[wave * 40 + (lane & 31)] = bits16(hv);
                h_all[(size_t)(b * T_ + t) * H_ + nidx] = hv;
            }
        }
        __syncthreads();   // B4
    }
}

// ---------- Kernel 3: out = sigmoid(h_all @ W_out.T + b_out) ----------
__global__ __launch_bounds__(256) void out_gemm(
    const float* __restrict__ h_all, const float* __restrict__ Wout,
    const float* __restrict__ bout, float* __restrict__ out)
{
    __shared__ __align__(16) float hs[32 * H_];
    const int tid  = threadIdx.x;
    const int row0 = blockIdx.x * 32;

    #pragma unroll
    for (int i = 0; i < 16; ++i) {
        int idx = i * 1024 + tid * 4;
        *(float4*)&hs[idx] = *(const float4*)&h_all[(size_t)row0 * H_ + idx];
    }
    __syncthreads();

    const int rg = tid >> 6;
    const int cg = tid & 63;
    const int c0 = cg * 4;
    float acc[8][4];
    #pragma unroll
    for (int r = 0; r < 8; ++r)
        #pragma unroll
        for (int c = 0; c < 4; ++c) acc[r][c] = 0.f;

    for (int k = 0; k < H_; k += 4) {
        float4 xq[8];
        #pragma unroll
        for (int r = 0; r < 8; ++r) xq[r] = *(float4*)&hs[(rg * 8 + r) * H_ + k];
        #pragma unroll
        for (int c = 0; c < 4; ++c) {
            float4 w4 = *(const float4*)&Wout[(size_t)(c0 + c) * H_ + k];
            #pragma unroll
            for (int r = 0; r < 8; ++r) acc[r][c] += dot4(xq[r], w4);
        }
    }
    #pragma unroll
    for (int r = 0; r < 8; ++r) {
        int grow = row0 + rg * 8 + r;
        float4 o4;
        o4.x = sigmoid_f(acc[r][0] + bout[c0 + 0]);
        o4.y = sigmoid_f(acc[r][1] + bout[c0 + 1]);
        o4.z = sigmoid_f(acc[r][2] + bout[c0 + 2]);
        o4.w = sigmoid_f(acc[r][3] + bout[c0 + 3]);
        *(float4*)&out[(size_t)grow * O_ + c0] = o4;
    }
}

extern "C" void kernel_launch(void* const* d_in, const int* in_sizes, int n_in,
                              void* d_out, int out_size, void* d_ws, size_t ws_size,
                              hipStream_t stream) {
    const float* x     = (const float*)d_in[0];
    const float* h0    = (const float*)d_in[1];
    const float* frf   = (const float*)d_in[2];
    const float* fwf   = (const float*)d_in[4];
    const float* m0    = (const float*)d_in[6];
    const float* Win   = (const float*)d_in[7];
    const float* bin   = (const float*)d_in[8];
    const float* Wread = (const float*)d_in[9];
    const float* bread = (const float*)d_in[10];
    const float* Wout  = (const float*)d_in[11];
    const float* bout  = (const float*)d_in[12];
    const float* Wkr   = (const float*)d_in[13];
    const float* bkr   = (const float*)d_in[14];
    const float* Wbr   = (const float*)d_in[15];
    const float* bbr   = (const float*)d_in[16];
    const float* Wgr   = (const float*)d_in[17];
    const float* bgr   = (const float*)d_in[18];
    const float* Wkw   = (const float*)d_in[19];
    const float* bkw   = (const float*)d_in[20];
    const float* Wbw   = (const float*)d_in[21];
    const float* bbw   = (const float*)d_in[22];
    const float* Wgw   = (const float*)d_in[23];
    const float* bgw   = (const float*)d_in[24];
    const float* We    = (const float*)d_in[25];
    const float* be    = (const float*)d_in[26];
    const float* Wa    = (const float*)d_in[27];
    const float* ba    = (const float*)d_in[28];

    unsigned short* xin_h = (unsigned short*)d_ws;                              // 8 MB
    float* h_all = (float*)((char*)d_ws + (size_t)B_ * T_ * H_ * 2);            // 16 MB
    unsigned short* Wh = (unsigned short*)((char*)d_ws + (size_t)B_ * T_ * H_ * 6);  // 256 KB

    w2h<<<128, 256, 0, stream>>>(Wkr, Wkw, We, Wa, Wh);
    xin_gemm<<<256, 256, 0, stream>>>(x, Win, bin, xin_h);
    ntm_loop<<<B_, 1024, 0, stream>>>(xin_h, h0, frf, fwf, m0,
        Wh, bkr, bkw, be, ba,
        Wbr, bbr, Wgr, bgr, Wbw, bbw, Wgw, bgw,
        Wread, bread, h_all);
    out_gemm<<<256, 256, 0, stream>>>(h_all, Wout, bout, (float*)d_out);
}